// Round 3
// baseline (2970.472 us; speedup 1.0000x reference)
//
#include <hip/hip_runtime.h>
#include <hip/hip_bf16.h>

// GCN link predictor, Round 3: bucketed partition + LDS-accumulated SPMM.
//
// Round-2 postmortem: per-edge CSR scatter showed WRITE_SIZE=292MB for a
// 25.6MB payload (11x write amplification) — random 4B stores spread over
// 400k lines from 8 non-coherent XCD L2s => partial-line write-back thrash.
//
// Round-3 structure:
//   bin_count   : hist[(dst>>8)*8 + blockIdx&7]++        (3128 counters)
//   bin_scan    : 1-block exclusive scan -> bscan (+sentinel), cur copy
//   bin_scatter : p = atomicAdd(cur[(dst>>8)*8+g]); payload[p]={key,val}
//                 key = (src<<8)|(dst&255); appends to 3128 frontiers =>
//                 full-line write-backs
//   spmm_bucket : block per 256-row bucket, output tile in LDS (64KB @ D=64),
//                 stream payload, lane d gathers in[src*D+d], LDS atomicAdd;
//                 bias(/ReLU) fused in the single coalesced output write.
// Row-level CSR (count/scan/scatter/rs) is gone entirely.

#define D_IN  256
#define D_HID 64
#define D_EMB 32
#define BROWS 256   // dst-rows per bucket
#define NGRP  8     // blockIdx&7 sub-split (reduces frontier sharing)

// ---------------------------------------------------------------------------
// GEMM1: h1[M,64] = x[M,256] @ W1[256,64]. W1 (64 KB) in LDS, 4x4 microtile.
__global__ __launch_bounds__(256) void gemm1_kernel(
    const float* __restrict__ x, const float* __restrict__ W1,
    float* __restrict__ h1, int M) {
  __shared__ float ws[D_IN * D_HID];
  const int tid = threadIdx.x;
  for (int i = tid; i < D_IN * D_HID / 4; i += 256)
    ((float4*)ws)[i] = ((const float4*)W1)[i];
  __syncthreads();

  const int row0 = blockIdx.x * 64;
  const int tr = tid >> 4;
  const int tc = tid & 15;

  int rows[4], rload[4];
  for (int i = 0; i < 4; ++i) {
    rows[i] = row0 + tr + 16 * i;
    rload[i] = rows[i] < M ? rows[i] : (M - 1);
  }

  float acc[4][4];
  for (int i = 0; i < 4; ++i)
    for (int j = 0; j < 4; ++j) acc[i][j] = 0.f;

  for (int k0 = 0; k0 < D_IN; k0 += 4) {
    float4 xv[4];
    for (int i = 0; i < 4; ++i)
      xv[i] = *(const float4*)&x[(long long)rload[i] * D_IN + k0];
    for (int kk = 0; kk < 4; ++kk) {
      const float4 wv = *(const float4*)&ws[(k0 + kk) * D_HID + tc * 4];
      for (int i = 0; i < 4; ++i) {
        const float a = (kk == 0) ? xv[i].x : (kk == 1) ? xv[i].y
                       : (kk == 2) ? xv[i].z : xv[i].w;
        acc[i][0] += a * wv.x;
        acc[i][1] += a * wv.y;
        acc[i][2] += a * wv.z;
        acc[i][3] += a * wv.w;
      }
    }
  }
  for (int i = 0; i < 4; ++i)
    if (rows[i] < M)
      *(float4*)&h1[(long long)rows[i] * D_HID + tc * 4] =
          make_float4(acc[i][0], acc[i][1], acc[i][2], acc[i][3]);
}

// ---------------------------------------------------------------------------
// Bucket partition
__global__ __launch_bounds__(256) void bin_count(
    const int* __restrict__ dst, int* __restrict__ hist, int nnz) {
  int e = blockIdx.x * 256 + threadIdx.x;
  int g = blockIdx.x & (NGRP - 1);
  if (e < nnz) atomicAdd(&hist[(dst[e] >> 8) * NGRP + g], 1);
}

// 1-block exclusive scan over ntot (<=4096) entries, in place; writes a copy
// to cur and the total as sentinel hist[ntot].
__global__ __launch_bounds__(256) void bin_scan(
    int* __restrict__ hist, int* __restrict__ cur, int ntot) {
  __shared__ int sm[256];
  const int t = threadIdx.x;
  const int per = (ntot + 255) / 256;  // <= 16
  const int base = t * per;
  int loc[16];
  int s = 0;
  for (int i = 0; i < per; ++i) {
    int idx = base + i;
    int v = (idx < ntot) ? hist[idx] : 0;
    loc[i] = s;
    s += v;
  }
  sm[t] = s;
  __syncthreads();
  for (int off = 1; off < 256; off <<= 1) {
    int tmp = (t >= off) ? sm[t - off] : 0;
    __syncthreads();
    sm[t] += tmp;
    __syncthreads();
  }
  const int b0 = sm[t] - s;  // exclusive thread base
  for (int i = 0; i < per; ++i) {
    int idx = base + i;
    if (idx < ntot) {
      int p = b0 + loc[i];
      hist[idx] = p;
      cur[idx] = p;
    }
  }
  if (t == 255) hist[ntot] = sm[255];  // sentinel = nnz
}

__global__ __launch_bounds__(256) void bin_scatter(
    const int* __restrict__ src, const int* __restrict__ dst,
    const float* __restrict__ val, int* __restrict__ cur,
    int2* __restrict__ payload, int nnz) {
  int e = blockIdx.x * 256 + threadIdx.x;
  int g = blockIdx.x & (NGRP - 1);
  if (e >= nnz) return;
  int d = dst[e];
  int p = atomicAdd(&cur[(d >> 8) * NGRP + g], 1);
  payload[p] = make_int2((src[e] << 8) | (d & (BROWS - 1)),
                         __float_as_int(val[e]));
}

// ---------------------------------------------------------------------------
// Bucketed SPMM: block b owns dst rows [b*256, b*256+256), tile in LDS.
// bstart[b*8] .. bstart[b*8+8] is the bucket's payload range (sentinel-backed).
template <int D, bool RELU>
__global__ __launch_bounds__(256) void spmm_bucket_kernel(
    const int* __restrict__ bstart, const int2* __restrict__ payload,
    const float* __restrict__ in, const float* __restrict__ bias,
    float* __restrict__ out, int M) {
  __shared__ float acc[BROWS * D];  // 64KB (D=64) / 32KB (D=32)
  const int tid = threadIdx.x;
  for (int i = tid; i < BROWS * D; i += 256) acc[i] = 0.f;
  __syncthreads();

  const int b = blockIdx.x;
  const int start = bstart[b * NGRP];
  const int end = bstart[b * NGRP + NGRP];

  constexpr int TEAM = D;            // lanes per edge
  constexpr int NT = 256 / TEAM;     // teams per block
  constexpr int U = 4;               // edge unroll
  const int team = tid / TEAM;
  const int lane = tid % TEAM;
  const int step = NT * U;
  const int nfull = ((end - start) / step) * step;

  for (int j = start + team * U; j < start + nfull; j += step) {
    float x[U], v[U];
    int dl[U];
#pragma unroll
    for (int u = 0; u < U; ++u) {
      int2 pk = payload[j + u];
      dl[u] = pk.x & (BROWS - 1);
      int s = pk.x >> 8;
      v[u] = __int_as_float(pk.y);
      x[u] = in[(long long)s * D + lane];
    }
#pragma unroll
    for (int u = 0; u < U; ++u)
      atomicAdd(&acc[dl[u] * D + lane], v[u] * x[u]);
  }
  for (int j = start + nfull + team; j < end; j += NT) {
    int2 pk = payload[j];
    int dl = pk.x & (BROWS - 1);
    int s = pk.x >> 8;
    float v = __int_as_float(pk.y);
    atomicAdd(&acc[dl * D + lane], v * in[(long long)s * D + lane]);
  }
  __syncthreads();

  const int row0 = b * BROWS;
  for (int i = tid; i < BROWS * D; i += 256) {
    int r = row0 + i / D;
    if (r < M) {
      float v = acc[i] + bias[i % D];
      if (RELU) v = fmaxf(v, 0.f);
      out[(long long)row0 * D + i] = v;
    }
  }
}

// ---------------------------------------------------------------------------
// GEMM2: h2[M,32] = z1[M,64] @ W2[64,32] (z1 already has bias+relu applied)
__global__ __launch_bounds__(256) void gemm2_kernel(
    const float* __restrict__ z1, const float* __restrict__ W2,
    float* __restrict__ h2, int M) {
  __shared__ float ws[D_HID * D_EMB];
  const int tid = threadIdx.x;
  for (int i = tid; i < D_HID * D_EMB / 4; i += 256)
    ((float4*)ws)[i] = ((const float4*)W2)[i];
  __syncthreads();

  const int row = blockIdx.x * 256 + tid;
  if (row >= M) return;

  float4 acc4[8];
  for (int c = 0; c < 8; ++c) acc4[c] = make_float4(0.f, 0.f, 0.f, 0.f);

  for (int k0 = 0; k0 < D_HID; k0 += 4) {
    float4 zv = *(const float4*)&z1[(long long)row * D_HID + k0];
    float av[4] = {zv.x, zv.y, zv.z, zv.w};
    for (int kk = 0; kk < 4; ++kk) {
      const float a = av[kk];
      const float4* wr = (const float4*)&ws[(k0 + kk) * D_EMB];
      for (int c = 0; c < 8; ++c) {
        float4 wv = wr[c];
        acc4[c].x += a * wv.x;
        acc4[c].y += a * wv.y;
        acc4[c].z += a * wv.z;
        acc4[c].w += a * wv.w;
      }
    }
  }
  float4* outp = (float4*)&h2[(long long)row * D_EMB];
  for (int c = 0; c < 8; ++c) outp[c] = acc4[c];
}

// ---------------------------------------------------------------------------
// Decoder: scores[e] = dot(z2[src], z2[dst])  (b2 already in z2)
__global__ __launch_bounds__(256) void decode_kernel(
    const int* __restrict__ ei, const float* __restrict__ z2,
    float* __restrict__ out, int nE) {
  const int e = blockIdx.x * 256 + threadIdx.x;
  if (e >= nE) return;
  const int s = ei[e];
  const int d = ei[nE + e];
  const float4* za = (const float4*)&z2[(long long)s * D_EMB];
  const float4* zb = (const float4*)&z2[(long long)d * D_EMB];
  float acc = 0.f;
  for (int c = 0; c < 8; ++c) {
    float4 a = za[c], b = zb[c];
    acc += a.x * b.x + a.y * b.y + a.z * b.z + a.w * b.w;
  }
  out[e] = acc;
}

// ---------------------------------------------------------------------------
extern "C" void kernel_launch(void* const* d_in, const int* in_sizes, int n_in,
                              void* d_out, int out_size, void* d_ws, size_t ws_size,
                              hipStream_t stream) {
  const float* x       = (const float*)d_in[0];
  const int*   adj_src = (const int*)d_in[1];
  const int*   adj_dst = (const int*)d_in[2];
  const float* adj_val = (const float*)d_in[3];
  const int*   ei      = (const int*)d_in[4];
  const float* W1      = (const float*)d_in[5];
  const float* b1      = (const float*)d_in[6];
  const float* W2      = (const float*)d_in[7];
  const float* b2      = (const float*)d_in[8];

  const int M   = in_sizes[0] / D_IN;      // 100000
  const int nnz = in_sizes[1];             // 3200000
  const int nE  = in_sizes[4] / 2;         // 2000000

  const int NBUK = (M + BROWS - 1) / BROWS;  // 391
  const int NTOT = NBUK * NGRP;              // 3128

  // Workspace (76.8 MB): h1 25.6 | z1 25.6 | payload 25.6
  char* ws = (char*)d_ws;
  float* h1      = (float*)(ws);
  float* z1      = (float*)(ws + (size_t)M * D_HID * 4);
  float* h2      = h1;  // h1 dead after SPMM1
  float* z2      = z1;  // z1 dead after GEMM2
  int2*  payload = (int2*)(ws + (size_t)M * D_HID * 8);

  // Small scratch in d_out (8 MB, dead until decode):
  //   bscan/hist: NTOT+1 ints @ 0;  cur: NTOT ints @ 4096
  int* bscan = (int*)d_out;
  int* cur   = (int*)d_out + 4096;

  // --- bucket partition ---
  hipMemsetAsync(bscan, 0, (size_t)(NTOT + 1) * 4, stream);
  bin_count<<<(nnz + 255) / 256, 256, 0, stream>>>(adj_dst, bscan, nnz);
  bin_scan<<<1, 256, 0, stream>>>(bscan, cur, NTOT);
  bin_scatter<<<(nnz + 255) / 256, 256, 0, stream>>>(
      adj_src, adj_dst, adj_val, cur, payload, nnz);

  // --- GEMM1 ---
  gemm1_kernel<<<(M + 63) / 64, 256, 0, stream>>>(x, W1, h1, M);

  // --- SPMM1 + b1 + ReLU ---
  spmm_bucket_kernel<D_HID, true><<<NBUK, 256, 0, stream>>>(
      bscan, payload, h1, b1, z1, M);

  // --- GEMM2 ---
  gemm2_kernel<<<(M + 255) / 256, 256, 0, stream>>>(z1, W2, h2, M);

  // --- SPMM2 + b2 ---
  spmm_bucket_kernel<D_EMB, false><<<NBUK, 256, 0, stream>>>(
      bscan, payload, h2, b2, z2, M);

  // --- Decode (overwrites d_out scratch) ---
  decode_kernel<<<(nE + 255) / 256, 256, 0, stream>>>(ei, z2, (float*)d_out, nE);
}

// Round 4
// 894.334 us; speedup vs baseline: 3.3214x; 3.3214x over previous
//
#include <hip/hip_runtime.h>
#include <hip/hip_bf16.h>

// GCN link predictor, Round 4: bucket partition + bucket-local counting sort
// -> packed CSR -> high-occupancy row-team SPMM.
//
// R2 postmortem: row-team CSR SPMM was fast (never in top-5, <220us) but the
// per-edge row scatter had 11x write amplification (292MB for 25.6MB).
// R3 postmortem: bucketed LDS-accumulate SPMM fixed writes but ran at 391
// blocks = 1.5 blocks/CU -> latency-bound disaster (VALUBusy 3%, 1362us).
//
// R4: partition edges into 391 x 256-row buckets (cheap, append-frontier
// writes), then one block per bucket counting-sorts its ~8200-edge segment
// into row order, writing a PACKED int2 CSR {src,val} into a bucket-local
// 64KB window (write-amp ~1) plus the global inclusive row scan rs. SPMM is
// the R2 row-team kernel (25000 blocks, full occupancy), 4x unrolled.

#define D_IN  256
#define D_HID 64
#define D_EMB 32
#define BROWS 256   // dst-rows per bucket
#define NGRP  8     // scatter sub-frontiers per bucket
#define NTOT_MAX 3200

// ---------------------------------------------------------------------------
// GEMM1: h1[M,64] = x[M,256] @ W1[256,64]. W1 (64 KB) in LDS, 4x4 microtile.
__global__ __launch_bounds__(256) void gemm1_kernel(
    const float* __restrict__ x, const float* __restrict__ W1,
    float* __restrict__ h1, int M) {
  __shared__ float ws[D_IN * D_HID];
  const int tid = threadIdx.x;
  for (int i = tid; i < D_IN * D_HID / 4; i += 256)
    ((float4*)ws)[i] = ((const float4*)W1)[i];
  __syncthreads();

  const int row0 = blockIdx.x * 64;
  const int tr = tid >> 4;
  const int tc = tid & 15;

  int rows[4], rload[4];
  for (int i = 0; i < 4; ++i) {
    rows[i] = row0 + tr + 16 * i;
    rload[i] = rows[i] < M ? rows[i] : (M - 1);
  }

  float acc[4][4];
  for (int i = 0; i < 4; ++i)
    for (int j = 0; j < 4; ++j) acc[i][j] = 0.f;

  for (int k0 = 0; k0 < D_IN; k0 += 4) {
    float4 xv[4];
    for (int i = 0; i < 4; ++i)
      xv[i] = *(const float4*)&x[(long long)rload[i] * D_IN + k0];
    for (int kk = 0; kk < 4; ++kk) {
      const float4 wv = *(const float4*)&ws[(k0 + kk) * D_HID + tc * 4];
      for (int i = 0; i < 4; ++i) {
        const float a = (kk == 0) ? xv[i].x : (kk == 1) ? xv[i].y
                       : (kk == 2) ? xv[i].z : xv[i].w;
        acc[i][0] += a * wv.x;
        acc[i][1] += a * wv.y;
        acc[i][2] += a * wv.z;
        acc[i][3] += a * wv.w;
      }
    }
  }
  for (int i = 0; i < 4; ++i)
    if (rows[i] < M)
      *(float4*)&h1[(long long)rows[i] * D_HID + tc * 4] =
          make_float4(acc[i][0], acc[i][1], acc[i][2], acc[i][3]);
}

// ---------------------------------------------------------------------------
// Bucket partition. Group of edge e must match bin_scatter: g = (e>>8)&7.
__global__ __launch_bounds__(256) void bin_count(
    const int* __restrict__ dst, int* __restrict__ hist, int nnz, int ntot) {
  __shared__ int h[NTOT_MAX];
  for (int i = threadIdx.x; i < ntot; i += 256) h[i] = 0;
  __syncthreads();
  const int stride = gridDim.x * 256;
  for (int e = blockIdx.x * 256 + threadIdx.x; e < nnz; e += stride) {
    int g = (e >> 8) & (NGRP - 1);
    atomicAdd(&h[(dst[e] >> 8) * NGRP + g], 1);
  }
  __syncthreads();
  for (int i = threadIdx.x; i < ntot; i += 256) {
    int v = h[i];
    if (v) atomicAdd(&hist[i], v);
  }
}

// 1-block exclusive scan over ntot (<=4096) entries, in place; copy to cur,
// total as sentinel hist[ntot].
__global__ __launch_bounds__(256) void bin_scan(
    int* __restrict__ hist, int* __restrict__ cur, int ntot) {
  __shared__ int sm[256];
  const int t = threadIdx.x;
  const int per = (ntot + 255) / 256;  // <= 16
  const int base = t * per;
  int loc[16];
  int s = 0;
  for (int i = 0; i < per; ++i) {
    int idx = base + i;
    int v = (idx < ntot) ? hist[idx] : 0;
    loc[i] = s;
    s += v;
  }
  sm[t] = s;
  __syncthreads();
  for (int off = 1; off < 256; off <<= 1) {
    int tmp = (t >= off) ? sm[t - off] : 0;
    __syncthreads();
    sm[t] += tmp;
    __syncthreads();
  }
  const int b0 = sm[t] - s;
  for (int i = 0; i < per; ++i) {
    int idx = base + i;
    if (idx < ntot) {
      int p = b0 + loc[i];
      hist[idx] = p;
      cur[idx] = p;
    }
  }
  if (t == 255) hist[ntot] = sm[255];  // sentinel = nnz
}

__global__ __launch_bounds__(256) void bin_scatter(
    const int* __restrict__ src, const int* __restrict__ dst,
    const float* __restrict__ val, int* __restrict__ cur,
    int2* __restrict__ payload, int nnz) {
  int e = blockIdx.x * 256 + threadIdx.x;
  int g = blockIdx.x & (NGRP - 1);  // == (e>>8)&7
  if (e >= nnz) return;
  int d = dst[e];
  int p = atomicAdd(&cur[(d >> 8) * NGRP + g], 1);
  payload[p] = make_int2((src[e] << 8) | (d & (BROWS - 1)),
                         __float_as_int(val[e]));
}

// ---------------------------------------------------------------------------
// Bucket-local counting sort: payload segment -> row-ordered packed CSR,
// plus global inclusive row scan rs. One block per bucket; all CSR writes
// land in the bucket's own [start,end) window (write-amp ~1).
__global__ __launch_bounds__(256) void bucket_sort_kernel(
    const int* __restrict__ bscan, const int2* __restrict__ payload,
    int2* __restrict__ csr, int* __restrict__ rs, int M) {
  __shared__ int sm[BROWS];
  __shared__ int cur[BROWS];
  const int b = blockIdx.x;
  const int t = threadIdx.x;
  const int start = bscan[b * NGRP];
  const int end = bscan[b * NGRP + NGRP];

  cur[t] = 0;  // reuse as count first
  __syncthreads();
  for (int j = start + t; j < end; j += 256)
    atomicAdd(&cur[payload[j].x & (BROWS - 1)], 1);
  __syncthreads();

  const int v = cur[t];
  sm[t] = v;
  __syncthreads();
  for (int off = 1; off < 256; off <<= 1) {
    int tmp = (t >= off) ? sm[t - off] : 0;
    __syncthreads();
    sm[t] += tmp;
    __syncthreads();
  }
  // sm[t] = inclusive scan of counts
  const int row = b * BROWS + t;
  if (row < M) rs[row] = start + sm[t];  // global inclusive row end
  __syncthreads();
  cur[t] = start + sm[t] - v;  // global exclusive cursor
  __syncthreads();

  for (int j = start + t; j < end; j += 256) {
    int2 pk = payload[j];
    int r = pk.x & (BROWS - 1);
    int p = atomicAdd(&cur[r], 1);
    csr[p] = make_int2(pk.x >> 8, pk.y);
  }
}

// ---------------------------------------------------------------------------
// Row-team CSR SPMM: out[row][d] = epilogue( sum val[j]*in[src[j]][d] )
// D lanes per row; rs is the INCLUSIVE scan (row i = [rs[i-1], rs[i])).
template <int D, bool RELU>
__global__ __launch_bounds__(256) void spmm_csr_kernel(
    const int* __restrict__ rs, const int2* __restrict__ csr,
    const float* __restrict__ in, const float* __restrict__ bias,
    float* __restrict__ out, int M) {
  const int lane = threadIdx.x % D;
  const int row = blockIdx.x * (256 / D) + threadIdx.x / D;
  if (row >= M) return;
  const int start = (row == 0) ? 0 : rs[row - 1];
  const int end = rs[row];
  float acc = 0.f;
  int j = start;
  for (; j + 4 <= end; j += 4) {
    int2 p0 = csr[j], p1 = csr[j + 1], p2 = csr[j + 2], p3 = csr[j + 3];
    float x0 = in[(long long)p0.x * D + lane];
    float x1 = in[(long long)p1.x * D + lane];
    float x2 = in[(long long)p2.x * D + lane];
    float x3 = in[(long long)p3.x * D + lane];
    acc = fmaf(__int_as_float(p0.y), x0, acc);
    acc = fmaf(__int_as_float(p1.y), x1, acc);
    acc = fmaf(__int_as_float(p2.y), x2, acc);
    acc = fmaf(__int_as_float(p3.y), x3, acc);
  }
  for (; j < end; ++j) {
    int2 pk = csr[j];
    acc = fmaf(__int_as_float(pk.y), in[(long long)pk.x * D + lane], acc);
  }
  float r = acc + bias[lane];
  if (RELU) r = fmaxf(r, 0.f);
  out[(long long)row * D + lane] = r;
}

// ---------------------------------------------------------------------------
// GEMM2: h2[M,32] = z1[M,64] @ W2[64,32] (z1 already has bias+relu applied)
__global__ __launch_bounds__(256) void gemm2_kernel(
    const float* __restrict__ z1, const float* __restrict__ W2,
    float* __restrict__ h2, int M) {
  __shared__ float ws[D_HID * D_EMB];
  const int tid = threadIdx.x;
  for (int i = tid; i < D_HID * D_EMB / 4; i += 256)
    ((float4*)ws)[i] = ((const float4*)W2)[i];
  __syncthreads();

  const int row = blockIdx.x * 256 + tid;
  if (row >= M) return;

  float4 acc4[8];
  for (int c = 0; c < 8; ++c) acc4[c] = make_float4(0.f, 0.f, 0.f, 0.f);

  for (int k0 = 0; k0 < D_HID; k0 += 4) {
    float4 zv = *(const float4*)&z1[(long long)row * D_HID + k0];
    float av[4] = {zv.x, zv.y, zv.z, zv.w};
    for (int kk = 0; kk < 4; ++kk) {
      const float a = av[kk];
      const float4* wr = (const float4*)&ws[(k0 + kk) * D_EMB];
      for (int c = 0; c < 8; ++c) {
        float4 wv = wr[c];
        acc4[c].x += a * wv.x;
        acc4[c].y += a * wv.y;
        acc4[c].z += a * wv.z;
        acc4[c].w += a * wv.w;
      }
    }
  }
  float4* outp = (float4*)&h2[(long long)row * D_EMB];
  for (int c = 0; c < 8; ++c) outp[c] = acc4[c];
}

// ---------------------------------------------------------------------------
// Decoder: scores[e] = dot(z2[src], z2[dst])  (b2 already in z2)
__global__ __launch_bounds__(256) void decode_kernel(
    const int* __restrict__ ei, const float* __restrict__ z2,
    float* __restrict__ out, int nE) {
  const int e = blockIdx.x * 256 + threadIdx.x;
  if (e >= nE) return;
  const int s = ei[e];
  const int d = ei[nE + e];
  const float4* za = (const float4*)&z2[(long long)s * D_EMB];
  const float4* zb = (const float4*)&z2[(long long)d * D_EMB];
  float acc = 0.f;
  for (int c = 0; c < 8; ++c) {
    float4 a = za[c], b = zb[c];
    acc += a.x * b.x + a.y * b.y + a.z * b.z + a.w * b.w;
  }
  out[e] = acc;
}

// ---------------------------------------------------------------------------
extern "C" void kernel_launch(void* const* d_in, const int* in_sizes, int n_in,
                              void* d_out, int out_size, void* d_ws, size_t ws_size,
                              hipStream_t stream) {
  const float* x       = (const float*)d_in[0];
  const int*   adj_src = (const int*)d_in[1];
  const int*   adj_dst = (const int*)d_in[2];
  const float* adj_val = (const float*)d_in[3];
  const int*   ei      = (const int*)d_in[4];
  const float* W1      = (const float*)d_in[5];
  const float* b1      = (const float*)d_in[6];
  const float* W2      = (const float*)d_in[7];
  const float* b2      = (const float*)d_in[8];

  const int M   = in_sizes[0] / D_IN;      // 100000
  const int nnz = in_sizes[1];             // 3200000
  const int nE  = in_sizes[4] / 2;         // 2000000

  const int NBUK = (M + BROWS - 1) / BROWS;  // 391
  const int NTOT = NBUK * NGRP;              // 3128

  // Workspace (76.8 MB):
  //   [0, 25.6):     csr packed int2 {src, val}
  //   [25.6, 51.2):  payload (dead after sort) -> then h1 (M*64), h2 reuse
  //   [51.2, 76.8):  z1 (M*64), z2 reuse
  char* ws = (char*)d_ws;
  int2*  csr     = (int2*)(ws);
  int2*  payload = (int2*)(ws + (size_t)nnz * 8);
  float* h1      = (float*)(ws + (size_t)nnz * 8);        // after payload dead
  float* z1      = (float*)(ws + (size_t)nnz * 8 + (size_t)M * D_HID * 4);
  float* h2      = h1;
  float* z2      = z1;

  // Small scratch in d_out (8 MB, dead until decode):
  //   rs: M ints @ 0; bscan: NTOT+1 ints @ 112k; cur: NTOT ints @ 120k
  int* rs    = (int*)d_out;
  int* bscan = (int*)d_out + 112 * 1024;
  int* cur   = (int*)d_out + 120 * 1024;

  // --- bucket partition ---
  hipMemsetAsync(bscan, 0, (size_t)(NTOT + 1) * 4, stream);
  bin_count<<<256, 256, 0, stream>>>(adj_dst, bscan, nnz, NTOT);
  bin_scan<<<1, 256, 0, stream>>>(bscan, cur, NTOT);
  bin_scatter<<<(nnz + 255) / 256, 256, 0, stream>>>(
      adj_src, adj_dst, adj_val, cur, payload, nnz);

  // --- bucket-local counting sort -> packed CSR + rs ---
  bucket_sort_kernel<<<NBUK, 256, 0, stream>>>(bscan, payload, csr, rs, M);

  // --- GEMM1 (overwrites payload region with h1) ---
  gemm1_kernel<<<(M + 63) / 64, 256, 0, stream>>>(x, W1, h1, M);

  // --- SPMM1 + b1 + ReLU ---
  spmm_csr_kernel<D_HID, true><<<(M + 3) / 4, 256, 0, stream>>>(
      rs, csr, h1, b1, z1, M);

  // --- GEMM2 ---
  gemm2_kernel<<<(M + 255) / 256, 256, 0, stream>>>(z1, W2, h2, M);

  // --- SPMM2 + b2 ---
  spmm_csr_kernel<D_EMB, false><<<(M + 7) / 8, 256, 0, stream>>>(
      rs, csr, h2, b2, z2, M);

  // --- Decode (overwrites d_out scratch) ---
  decode_kernel<<<(nE + 255) / 256, 256, 0, stream>>>(ei, z2, (float*)d_out, nE);
}

// Round 5
// 651.172 us; speedup vs baseline: 4.5617x; 1.3734x over previous
//
#include <hip/hip_runtime.h>
#include <hip/hip_bf16.h>

// GCN link predictor, Round 5: tile-staged partition (LDS multi-split).
//
// R4 postmortem: bin_scatter = 296us, WRITE_SIZE 130MB for a 25.6MB payload
// (5x write-amp) — 3128 concurrently-moving 8B-append frontiers leave nearly
// every 128B line partially dirty across 8 non-coherent XCD L2s.
//
// R5 partition: one block per 4096-edge tile:
//   LDS histogram (391 buckets) -> block scan -> ONE global atomicAdd per
//   (tile,bucket) reserving a contiguous chunk -> LDS counting sort ->
//   contiguous run writes (~84B runs) => write-amp ~1.5-2.
// NGRP sub-frontiers removed everywhere (contention now batched).
// Rest of pipeline unchanged from R4 (bucket_sort -> packed CSR -> row-team
// SPMM at full occupancy; GEMMs; fused biases; decode).

#define D_IN  256
#define D_HID 64
#define D_EMB 32
#define BROWS 256       // dst-rows per bucket
#define NBUK_MAX 512    // >= ceil(M/BROWS) = 391
#define TILE  4096      // edges per partition tile (16/thread)

// ---------------------------------------------------------------------------
// GEMM1: h1[M,64] = x[M,256] @ W1[256,64]. W1 (64 KB) in LDS, 4x4 microtile.
__global__ __launch_bounds__(256) void gemm1_kernel(
    const float* __restrict__ x, const float* __restrict__ W1,
    float* __restrict__ h1, int M) {
  __shared__ float ws[D_IN * D_HID];
  const int tid = threadIdx.x;
  for (int i = tid; i < D_IN * D_HID / 4; i += 256)
    ((float4*)ws)[i] = ((const float4*)W1)[i];
  __syncthreads();

  const int row0 = blockIdx.x * 64;
  const int tr = tid >> 4;
  const int tc = tid & 15;

  int rows[4], rload[4];
  for (int i = 0; i < 4; ++i) {
    rows[i] = row0 + tr + 16 * i;
    rload[i] = rows[i] < M ? rows[i] : (M - 1);
  }

  float acc[4][4];
  for (int i = 0; i < 4; ++i)
    for (int j = 0; j < 4; ++j) acc[i][j] = 0.f;

  for (int k0 = 0; k0 < D_IN; k0 += 4) {
    float4 xv[4];
    for (int i = 0; i < 4; ++i)
      xv[i] = *(const float4*)&x[(long long)rload[i] * D_IN + k0];
    for (int kk = 0; kk < 4; ++kk) {
      const float4 wv = *(const float4*)&ws[(k0 + kk) * D_HID + tc * 4];
      for (int i = 0; i < 4; ++i) {
        const float a = (kk == 0) ? xv[i].x : (kk == 1) ? xv[i].y
                       : (kk == 2) ? xv[i].z : xv[i].w;
        acc[i][0] += a * wv.x;
        acc[i][1] += a * wv.y;
        acc[i][2] += a * wv.z;
        acc[i][3] += a * wv.w;
      }
    }
  }
  for (int i = 0; i < 4; ++i)
    if (rows[i] < M)
      *(float4*)&h1[(long long)rows[i] * D_HID + tc * 4] =
          make_float4(acc[i][0], acc[i][1], acc[i][2], acc[i][3]);
}

// ---------------------------------------------------------------------------
// Bucket histogram (LDS-staged), nbuk counters.
__global__ __launch_bounds__(256) void bin_count(
    const int* __restrict__ dst, int* __restrict__ hist, int nnz, int nbuk) {
  __shared__ int h[NBUK_MAX];
  for (int i = threadIdx.x; i < nbuk; i += 256) h[i] = 0;
  __syncthreads();
  const int stride = gridDim.x * 256;
  for (int e = blockIdx.x * 256 + threadIdx.x; e < nnz; e += stride)
    atomicAdd(&h[dst[e] >> 8], 1);
  __syncthreads();
  for (int i = threadIdx.x; i < nbuk; i += 256) {
    int v = h[i];
    if (v) atomicAdd(&hist[i], v);
  }
}

// 1-block exclusive scan (in place), copy to cur, sentinel hist[n] = total.
__global__ __launch_bounds__(256) void bin_scan(
    int* __restrict__ hist, int* __restrict__ cur, int n) {
  __shared__ int sm[256];
  const int t = threadIdx.x;
  const int per = (n + 255) / 256;  // <= 2 for n=391
  const int base = t * per;
  int loc[4];
  int s = 0;
  for (int i = 0; i < per; ++i) {
    int idx = base + i;
    int v = (idx < n) ? hist[idx] : 0;
    loc[i] = s;
    s += v;
  }
  sm[t] = s;
  __syncthreads();
  for (int off = 1; off < 256; off <<= 1) {
    int tmp = (t >= off) ? sm[t - off] : 0;
    __syncthreads();
    sm[t] += tmp;
    __syncthreads();
  }
  const int b0 = sm[t] - s;
  for (int i = 0; i < per; ++i) {
    int idx = base + i;
    if (idx < n) {
      int p = b0 + loc[i];
      hist[idx] = p;
      cur[idx] = p;
    }
  }
  if (t == 255) hist[n] = sm[255];  // sentinel = nnz
}

// ---------------------------------------------------------------------------
// Tile-staged partition: per 4096-edge tile, LDS histogram -> scan -> one
// global reservation per (tile,bucket) -> LDS counting sort -> contiguous
// run writes into each bucket's reserved chunk.
__global__ __launch_bounds__(256) void partition_kernel(
    const int* __restrict__ src, const int* __restrict__ dst,
    const float* __restrict__ val, int* __restrict__ cur,
    int2* __restrict__ payload, int nnz, int nbuk) {
  __shared__ int2 stage[TILE];            // 32 KB
  __shared__ unsigned short sbkt[TILE];   // 8 KB
  __shared__ int hist[NBUK_MAX];          // counts -> local excl offsets
  __shared__ int lcur[NBUK_MAX];
  __shared__ int gbase[NBUK_MAX];
  __shared__ int sm[256];

  const int t = threadIdx.x;
  const long long base = (long long)blockIdx.x * TILE;
  const int cnt = min(TILE, (int)(nnz - base));

  for (int i = t; i < nbuk; i += 256) hist[i] = 0;
  __syncthreads();

  // load edges + LDS histogram
  constexpr int PER = TILE / 256;  // 16
  int key[PER], vv[PER];
  short bk[PER];
  for (int i = 0; i < PER; ++i) {
    int idx = t + i * 256;
    if (idx < cnt) {
      int d = dst[base + idx];
      int b = d >> 8;
      bk[i] = (short)b;
      key[i] = (src[base + idx] << 8) | (d & (BROWS - 1));
      vv[i] = __float_as_int(val[base + idx]);
      atomicAdd(&hist[b], 1);
    } else {
      bk[i] = -1;
    }
  }
  __syncthreads();

  // scan hist -> exclusive offsets; reserve global chunks
  {
    const int per = (nbuk + 255) / 256;  // 2
    int c[4], loc[4];
    int s = 0;
    for (int i = 0; i < per; ++i) {
      int idx = t * per + i;
      c[i] = (idx < nbuk) ? hist[idx] : 0;
      loc[i] = s;
      s += c[i];
    }
    sm[t] = s;
    __syncthreads();
    for (int off = 1; off < 256; off <<= 1) {
      int tmp = (t >= off) ? sm[t - off] : 0;
      __syncthreads();
      sm[t] += tmp;
      __syncthreads();
    }
    const int b0 = sm[t] - s;
    for (int i = 0; i < per; ++i) {
      int idx = t * per + i;
      if (idx < nbuk) {
        int off = b0 + loc[i];
        hist[idx] = off;   // local exclusive offset
        lcur[idx] = off;
        if (c[i] > 0) gbase[idx] = atomicAdd(&cur[idx], c[i]);
      }
    }
  }
  __syncthreads();

  // counting sort into stage
  for (int i = 0; i < PER; ++i) {
    if (bk[i] >= 0) {
      int p = atomicAdd(&lcur[bk[i]], 1);
      stage[p] = make_int2(key[i], vv[i]);
      sbkt[p] = (unsigned short)bk[i];
    }
  }
  __syncthreads();

  // contiguous run write-out
  for (int i = t; i < cnt; i += 256) {
    int b = sbkt[i];
    payload[gbase[b] + (i - hist[b])] = stage[i];
  }
}

// ---------------------------------------------------------------------------
// Bucket-local counting sort: payload segment -> row-ordered packed CSR,
// plus global inclusive row scan rs. One block per bucket.
__global__ __launch_bounds__(256) void bucket_sort_kernel(
    const int* __restrict__ bscan, const int2* __restrict__ payload,
    int2* __restrict__ csr, int* __restrict__ rs, int M) {
  __shared__ int sm[BROWS];
  __shared__ int cur[BROWS];
  const int b = blockIdx.x;
  const int t = threadIdx.x;
  const int start = bscan[b];
  const int end = bscan[b + 1];

  cur[t] = 0;
  __syncthreads();
  for (int j = start + t; j < end; j += 256)
    atomicAdd(&cur[payload[j].x & (BROWS - 1)], 1);
  __syncthreads();

  const int v = cur[t];
  sm[t] = v;
  __syncthreads();
  for (int off = 1; off < 256; off <<= 1) {
    int tmp = (t >= off) ? sm[t - off] : 0;
    __syncthreads();
    sm[t] += tmp;
    __syncthreads();
  }
  const int row = b * BROWS + t;
  if (row < M) rs[row] = start + sm[t];  // global inclusive row end
  __syncthreads();
  cur[t] = start + sm[t] - v;            // global exclusive cursor
  __syncthreads();

  for (int j = start + t; j < end; j += 256) {
    int2 pk = payload[j];
    int r = pk.x & (BROWS - 1);
    int p = atomicAdd(&cur[r], 1);
    csr[p] = make_int2(pk.x >> 8, pk.y);
  }
}

// ---------------------------------------------------------------------------
// Row-team CSR SPMM: D lanes per row; rs is the INCLUSIVE row scan.
template <int D, bool RELU>
__global__ __launch_bounds__(256) void spmm_csr_kernel(
    const int* __restrict__ rs, const int2* __restrict__ csr,
    const float* __restrict__ in, const float* __restrict__ bias,
    float* __restrict__ out, int M) {
  const int lane = threadIdx.x % D;
  const int row = blockIdx.x * (256 / D) + threadIdx.x / D;
  if (row >= M) return;
  const int start = (row == 0) ? 0 : rs[row - 1];
  const int end = rs[row];
  float acc = 0.f;
  int j = start;
  for (; j + 4 <= end; j += 4) {
    int2 p0 = csr[j], p1 = csr[j + 1], p2 = csr[j + 2], p3 = csr[j + 3];
    float x0 = in[(long long)p0.x * D + lane];
    float x1 = in[(long long)p1.x * D + lane];
    float x2 = in[(long long)p2.x * D + lane];
    float x3 = in[(long long)p3.x * D + lane];
    acc = fmaf(__int_as_float(p0.y), x0, acc);
    acc = fmaf(__int_as_float(p1.y), x1, acc);
    acc = fmaf(__int_as_float(p2.y), x2, acc);
    acc = fmaf(__int_as_float(p3.y), x3, acc);
  }
  for (; j < end; ++j) {
    int2 pk = csr[j];
    acc = fmaf(__int_as_float(pk.y), in[(long long)pk.x * D + lane], acc);
  }
  float r = acc + bias[lane];
  if (RELU) r = fmaxf(r, 0.f);
  out[(long long)row * D + lane] = r;
}

// ---------------------------------------------------------------------------
// GEMM2: h2[M,32] = z1[M,64] @ W2[64,32]
__global__ __launch_bounds__(256) void gemm2_kernel(
    const float* __restrict__ z1, const float* __restrict__ W2,
    float* __restrict__ h2, int M) {
  __shared__ float ws[D_HID * D_EMB];
  const int tid = threadIdx.x;
  for (int i = tid; i < D_HID * D_EMB / 4; i += 256)
    ((float4*)ws)[i] = ((const float4*)W2)[i];
  __syncthreads();

  const int row = blockIdx.x * 256 + tid;
  if (row >= M) return;

  float4 acc4[8];
  for (int c = 0; c < 8; ++c) acc4[c] = make_float4(0.f, 0.f, 0.f, 0.f);

  for (int k0 = 0; k0 < D_HID; k0 += 4) {
    float4 zv = *(const float4*)&z1[(long long)row * D_HID + k0];
    float av[4] = {zv.x, zv.y, zv.z, zv.w};
    for (int kk = 0; kk < 4; ++kk) {
      const float a = av[kk];
      const float4* wr = (const float4*)&ws[(k0 + kk) * D_EMB];
      for (int c = 0; c < 8; ++c) {
        float4 wv = wr[c];
        acc4[c].x += a * wv.x;
        acc4[c].y += a * wv.y;
        acc4[c].z += a * wv.z;
        acc4[c].w += a * wv.w;
      }
    }
  }
  float4* outp = (float4*)&h2[(long long)row * D_EMB];
  for (int c = 0; c < 8; ++c) outp[c] = acc4[c];
}

// ---------------------------------------------------------------------------
// Decoder: scores[e] = dot(z2[src], z2[dst])
__global__ __launch_bounds__(256) void decode_kernel(
    const int* __restrict__ ei, const float* __restrict__ z2,
    float* __restrict__ out, int nE) {
  const int e = blockIdx.x * 256 + threadIdx.x;
  if (e >= nE) return;
  const int s = ei[e];
  const int d = ei[nE + e];
  const float4* za = (const float4*)&z2[(long long)s * D_EMB];
  const float4* zb = (const float4*)&z2[(long long)d * D_EMB];
  float acc = 0.f;
  for (int c = 0; c < 8; ++c) {
    float4 a = za[c], b = zb[c];
    acc += a.x * b.x + a.y * b.y + a.z * b.z + a.w * b.w;
  }
  out[e] = acc;
}

// ---------------------------------------------------------------------------
extern "C" void kernel_launch(void* const* d_in, const int* in_sizes, int n_in,
                              void* d_out, int out_size, void* d_ws, size_t ws_size,
                              hipStream_t stream) {
  const float* x       = (const float*)d_in[0];
  const int*   adj_src = (const int*)d_in[1];
  const int*   adj_dst = (const int*)d_in[2];
  const float* adj_val = (const float*)d_in[3];
  const int*   ei      = (const int*)d_in[4];
  const float* W1      = (const float*)d_in[5];
  const float* b1      = (const float*)d_in[6];
  const float* W2      = (const float*)d_in[7];
  const float* b2      = (const float*)d_in[8];

  const int M   = in_sizes[0] / D_IN;      // 100000
  const int nnz = in_sizes[1];             // 3200000
  const int nE  = in_sizes[4] / 2;         // 2000000

  const int NBUK = (M + BROWS - 1) / BROWS;  // 391

  // Workspace (76.8 MB):
  //   [0, 25.6):     csr packed int2 {src, val}
  //   [25.6, 51.2):  payload (dead after sort) -> h1 (M*64), h2 reuse
  //   [51.2, 76.8):  z1 (M*64), z2 reuse
  char* ws = (char*)d_ws;
  int2*  csr     = (int2*)(ws);
  int2*  payload = (int2*)(ws + (size_t)nnz * 8);
  float* h1      = (float*)(ws + (size_t)nnz * 8);
  float* z1      = (float*)(ws + (size_t)nnz * 8 + (size_t)M * D_HID * 4);
  float* h2      = h1;
  float* z2      = z1;

  // Small scratch in d_out (8 MB, dead until decode):
  int* rs    = (int*)d_out;                 // M ints
  int* bscan = (int*)d_out + 112 * 1024;    // NBUK+1 ints
  int* cur   = (int*)d_out + 120 * 1024;    // NBUK ints

  // --- bucket partition ---
  hipMemsetAsync(bscan, 0, (size_t)(NBUK + 1) * 4, stream);
  bin_count<<<256, 256, 0, stream>>>(adj_dst, bscan, nnz, NBUK);
  bin_scan<<<1, 256, 0, stream>>>(bscan, cur, NBUK);
  partition_kernel<<<(nnz + TILE - 1) / TILE, 256, 0, stream>>>(
      adj_src, adj_dst, adj_val, cur, payload, nnz, NBUK);

  // --- bucket-local counting sort -> packed CSR + rs ---
  bucket_sort_kernel<<<NBUK, 256, 0, stream>>>(bscan, payload, csr, rs, M);

  // --- GEMM1 (overwrites payload region with h1) ---
  gemm1_kernel<<<(M + 63) / 64, 256, 0, stream>>>(x, W1, h1, M);

  // --- SPMM1 + b1 + ReLU ---
  spmm_csr_kernel<D_HID, true><<<(M + 3) / 4, 256, 0, stream>>>(
      rs, csr, h1, b1, z1, M);

  // --- GEMM2 ---
  gemm2_kernel<<<(M + 255) / 256, 256, 0, stream>>>(z1, W2, h2, M);

  // --- SPMM2 + b2 ---
  spmm_csr_kernel<D_EMB, false><<<(M + 7) / 8, 256, 0, stream>>>(
      rs, csr, h2, b2, z2, M);

  // --- Decode (overwrites d_out scratch) ---
  decode_kernel<<<(nE + 255) / 256, 256, 0, stream>>>(ei, z2, (float*)d_out, nE);
}

// Round 6
// 579.864 us; speedup vs baseline: 5.1227x; 1.1230x over previous
//
#include <hip/hip_runtime.h>
#include <hip/hip_bf16.h>

// GCN link predictor, Round 6: bf16 features + 4-byte packed CSR.
//
// R5 postmortem: spmm_csr<64> top at 121us, FETCH 358MB vs 25.6MB resident
// h1 — gathers replicate h1 across 8 XCD L2s and still miss ~44% of the
// 819MB logical volume. Gather-traffic-bound (VALUBusy 31%). Volume is
// nnz*D*elem — so shrink elem: bf16 features (fp32 accum, 0.4% rel err vs
// threshold 1638 @ scores ~256) and CSR packed to 4B/edge
// (src:17b | val:15b fixed-point, err 1.5e-5).
// Pipeline: bin_count -> bin_scan -> tile partition (8B payload) ->
// bucket sort (emits 4B CSR + inclusive rs) -> gemm1(fp32 in, bf16 out) ->
// spmm1(+b1+relu) -> gemm2 -> spmm2(+b2) -> decode.

#define D_IN  256
#define D_HID 64
#define D_EMB 32
#define BROWS 256       // dst-rows per bucket
#define NBUK_MAX 512    // >= ceil(M/BROWS) = 391
#define TILE  4096      // edges per partition tile (16/thread)

typedef unsigned short u16;
typedef unsigned int u32;

__device__ __forceinline__ float bf2f(u32 u) {
  return __uint_as_float((u & 0xFFFFu) << 16);
}
__device__ __forceinline__ u16 f2bf(float f) {
  u32 x = __float_as_uint(f);
  x += 0x7FFFu + ((x >> 16) & 1u);  // RNE
  return (u16)(x >> 16);
}
__device__ __forceinline__ void unpack8(uint4 u, float* f) {
  f[0] = bf2f(u.x); f[1] = bf2f(u.x >> 16);
  f[2] = bf2f(u.y); f[3] = bf2f(u.y >> 16);
  f[4] = bf2f(u.z); f[5] = bf2f(u.z >> 16);
  f[6] = bf2f(u.w); f[7] = bf2f(u.w >> 16);
}

// ---------------------------------------------------------------------------
// GEMM1: h1[M,64](bf16) = x[M,256](f32) @ W1[256,64](f32). W1 in LDS.
__global__ __launch_bounds__(256) void gemm1_kernel(
    const float* __restrict__ x, const float* __restrict__ W1,
    u16* __restrict__ h1, int M) {
  __shared__ float ws[D_IN * D_HID];
  const int tid = threadIdx.x;
  for (int i = tid; i < D_IN * D_HID / 4; i += 256)
    ((float4*)ws)[i] = ((const float4*)W1)[i];
  __syncthreads();

  const int row0 = blockIdx.x * 64;
  const int tr = tid >> 4;
  const int tc = tid & 15;

  int rows[4], rload[4];
  for (int i = 0; i < 4; ++i) {
    rows[i] = row0 + tr + 16 * i;
    rload[i] = rows[i] < M ? rows[i] : (M - 1);
  }

  float acc[4][4];
  for (int i = 0; i < 4; ++i)
    for (int j = 0; j < 4; ++j) acc[i][j] = 0.f;

  for (int k0 = 0; k0 < D_IN; k0 += 4) {
    float4 xv[4];
    for (int i = 0; i < 4; ++i)
      xv[i] = *(const float4*)&x[(long long)rload[i] * D_IN + k0];
    for (int kk = 0; kk < 4; ++kk) {
      const float4 wv = *(const float4*)&ws[(k0 + kk) * D_HID + tc * 4];
      for (int i = 0; i < 4; ++i) {
        const float a = (kk == 0) ? xv[i].x : (kk == 1) ? xv[i].y
                       : (kk == 2) ? xv[i].z : xv[i].w;
        acc[i][0] += a * wv.x;
        acc[i][1] += a * wv.y;
        acc[i][2] += a * wv.z;
        acc[i][3] += a * wv.w;
      }
    }
  }
  for (int i = 0; i < 4; ++i)
    if (rows[i] < M) {
      ushort4 o;
      o.x = f2bf(acc[i][0]); o.y = f2bf(acc[i][1]);
      o.z = f2bf(acc[i][2]); o.w = f2bf(acc[i][3]);
      *(ushort4*)&h1[(long long)rows[i] * D_HID + tc * 4] = o;
    }
}

// ---------------------------------------------------------------------------
// Bucket histogram (LDS-staged).
__global__ __launch_bounds__(256) void bin_count(
    const int* __restrict__ dst, int* __restrict__ hist, int nnz, int nbuk) {
  __shared__ int h[NBUK_MAX];
  for (int i = threadIdx.x; i < nbuk; i += 256) h[i] = 0;
  __syncthreads();
  const int stride = gridDim.x * 256;
  for (int e = blockIdx.x * 256 + threadIdx.x; e < nnz; e += stride)
    atomicAdd(&h[dst[e] >> 8], 1);
  __syncthreads();
  for (int i = threadIdx.x; i < nbuk; i += 256) {
    int v = h[i];
    if (v) atomicAdd(&hist[i], v);
  }
}

// 1-block exclusive scan (in place), copy to cur, sentinel hist[n] = total.
__global__ __launch_bounds__(256) void bin_scan(
    int* __restrict__ hist, int* __restrict__ cur, int n) {
  __shared__ int sm[256];
  const int t = threadIdx.x;
  const int per = (n + 255) / 256;
  const int base = t * per;
  int loc[4];
  int s = 0;
  for (int i = 0; i < per; ++i) {
    int idx = base + i;
    int v = (idx < n) ? hist[idx] : 0;
    loc[i] = s;
    s += v;
  }
  sm[t] = s;
  __syncthreads();
  for (int off = 1; off < 256; off <<= 1) {
    int tmp = (t >= off) ? sm[t - off] : 0;
    __syncthreads();
    sm[t] += tmp;
    __syncthreads();
  }
  const int b0 = sm[t] - s;
  for (int i = 0; i < per; ++i) {
    int idx = base + i;
    if (idx < n) {
      int p = b0 + loc[i];
      hist[idx] = p;
      cur[idx] = p;
    }
  }
  if (t == 255) hist[n] = sm[255];
}

// ---------------------------------------------------------------------------
// Tile-staged partition: LDS histogram -> scan -> one global reservation per
// (tile,bucket) -> LDS counting sort -> contiguous run writes.
__global__ __launch_bounds__(256) void partition_kernel(
    const int* __restrict__ src, const int* __restrict__ dst,
    const float* __restrict__ val, int* __restrict__ cur,
    int2* __restrict__ payload, int nnz, int nbuk) {
  __shared__ int2 stage[TILE];            // 32 KB
  __shared__ u16 sbkt[TILE];              // 8 KB
  __shared__ int hist[NBUK_MAX];
  __shared__ int lcur[NBUK_MAX];
  __shared__ int gbase[NBUK_MAX];
  __shared__ int sm[256];

  const int t = threadIdx.x;
  const long long base = (long long)blockIdx.x * TILE;
  const int cnt = min(TILE, (int)(nnz - base));

  for (int i = t; i < nbuk; i += 256) hist[i] = 0;
  __syncthreads();

  constexpr int PER = TILE / 256;  // 16
  int key[PER], vv[PER];
  short bk[PER];
  for (int i = 0; i < PER; ++i) {
    int idx = t + i * 256;
    if (idx < cnt) {
      int d = dst[base + idx];
      int b = d >> 8;
      bk[i] = (short)b;
      key[i] = (src[base + idx] << 8) | (d & (BROWS - 1));
      vv[i] = __float_as_int(val[base + idx]);
      atomicAdd(&hist[b], 1);
    } else {
      bk[i] = -1;
    }
  }
  __syncthreads();

  {
    const int per = (nbuk + 255) / 256;  // 2
    int c[4], loc[4];
    int s = 0;
    for (int i = 0; i < per; ++i) {
      int idx = t * per + i;
      c[i] = (idx < nbuk) ? hist[idx] : 0;
      loc[i] = s;
      s += c[i];
    }
    sm[t] = s;
    __syncthreads();
    for (int off = 1; off < 256; off <<= 1) {
      int tmp = (t >= off) ? sm[t - off] : 0;
      __syncthreads();
      sm[t] += tmp;
      __syncthreads();
    }
    const int b0 = sm[t] - s;
    for (int i = 0; i < per; ++i) {
      int idx = t * per + i;
      if (idx < nbuk) {
        int off = b0 + loc[i];
        hist[idx] = off;
        lcur[idx] = off;
        if (c[i] > 0) gbase[idx] = atomicAdd(&cur[idx], c[i]);
      }
    }
  }
  __syncthreads();

  for (int i = 0; i < PER; ++i) {
    if (bk[i] >= 0) {
      int p = atomicAdd(&lcur[bk[i]], 1);
      stage[p] = make_int2(key[i], vv[i]);
      sbkt[p] = (u16)bk[i];
    }
  }
  __syncthreads();

  for (int i = t; i < cnt; i += 256) {
    int b = sbkt[i];
    payload[gbase[b] + (i - hist[b])] = stage[i];
  }
}

// ---------------------------------------------------------------------------
// Bucket-local counting sort -> 4B packed CSR (src:17b | val:15b fixed-point)
// + global inclusive row scan rs. One block per bucket.
__global__ __launch_bounds__(256) void bucket_sort_kernel(
    const int* __restrict__ bscan, const int2* __restrict__ payload,
    u32* __restrict__ csr, int* __restrict__ rs, int M) {
  __shared__ int sm[BROWS];
  __shared__ int cur[BROWS];
  const int b = blockIdx.x;
  const int t = threadIdx.x;
  const int start = bscan[b];
  const int end = bscan[b + 1];

  cur[t] = 0;
  __syncthreads();
  for (int j = start + t; j < end; j += 256)
    atomicAdd(&cur[payload[j].x & (BROWS - 1)], 1);
  __syncthreads();

  const int v = cur[t];
  sm[t] = v;
  __syncthreads();
  for (int off = 1; off < 256; off <<= 1) {
    int tmp = (t >= off) ? sm[t - off] : 0;
    __syncthreads();
    sm[t] += tmp;
    __syncthreads();
  }
  const int row = b * BROWS + t;
  if (row < M) rs[row] = start + sm[t];
  __syncthreads();
  cur[t] = start + sm[t] - v;
  __syncthreads();

  for (int j = start + t; j < end; j += 256) {
    int2 pk = payload[j];
    int r = pk.x & (BROWS - 1);
    int p = atomicAdd(&cur[r], 1);
    float fv = __int_as_float(pk.y);
    int q = (int)(fv * 32768.f + 0.5f);
    q = min(q, 32767);
    csr[p] = ((u32)(pk.x >> 8) << 15) | (u32)q;
  }
}

// ---------------------------------------------------------------------------
// Row-team CSR SPMM (bf16 in/out, fp32 accum). rs = inclusive row scan.
template <int D, bool RELU>
__global__ __launch_bounds__(256) void spmm_csr_kernel(
    const int* __restrict__ rs, const u32* __restrict__ csr,
    const u16* __restrict__ in, const float* __restrict__ bias,
    u16* __restrict__ out, int M) {
  const int lane = threadIdx.x % D;
  const int row = blockIdx.x * (256 / D) + threadIdx.x / D;
  if (row >= M) return;
  const int start = (row == 0) ? 0 : rs[row - 1];
  const int end = rs[row];
  const float qs = 1.f / 32768.f;
  float acc = 0.f;
  int j = start;
  for (; j + 4 <= end; j += 4) {
    u32 p0 = csr[j], p1 = csr[j + 1], p2 = csr[j + 2], p3 = csr[j + 3];
    float x0 = bf2f(in[(long long)(p0 >> 15) * D + lane]);
    float x1 = bf2f(in[(long long)(p1 >> 15) * D + lane]);
    float x2 = bf2f(in[(long long)(p2 >> 15) * D + lane]);
    float x3 = bf2f(in[(long long)(p3 >> 15) * D + lane]);
    acc = fmaf((float)(p0 & 32767u) * qs, x0, acc);
    acc = fmaf((float)(p1 & 32767u) * qs, x1, acc);
    acc = fmaf((float)(p2 & 32767u) * qs, x2, acc);
    acc = fmaf((float)(p3 & 32767u) * qs, x3, acc);
  }
  for (; j < end; ++j) {
    u32 pk = csr[j];
    acc = fmaf((float)(pk & 32767u) * qs,
               bf2f(in[(long long)(pk >> 15) * D + lane]), acc);
  }
  float r = acc + bias[lane];
  if (RELU) r = fmaxf(r, 0.f);
  out[(long long)row * D + lane] = f2bf(r);
}

// ---------------------------------------------------------------------------
// GEMM2: h2[M,32](bf16) = z1[M,64](bf16) @ W2[64,32](f32)
__global__ __launch_bounds__(256) void gemm2_kernel(
    const u16* __restrict__ z1, const float* __restrict__ W2,
    u16* __restrict__ h2, int M) {
  __shared__ float ws[D_HID * D_EMB];
  const int tid = threadIdx.x;
  for (int i = tid; i < D_HID * D_EMB / 4; i += 256)
    ((float4*)ws)[i] = ((const float4*)W2)[i];
  __syncthreads();

  const int row = blockIdx.x * 256 + tid;
  if (row >= M) return;

  float4 acc4[8];
  for (int c = 0; c < 8; ++c) acc4[c] = make_float4(0.f, 0.f, 0.f, 0.f);

  const uint4* zr = (const uint4*)&z1[(long long)row * D_HID];
  for (int blk = 0; blk < 8; ++blk) {
    float a8[8];
    unpack8(zr[blk], a8);
    for (int kk = 0; kk < 8; ++kk) {
      const float a = a8[kk];
      const float4* wr = (const float4*)&ws[(blk * 8 + kk) * D_EMB];
      for (int c = 0; c < 8; ++c) {
        float4 wv = wr[c];
        acc4[c].x += a * wv.x;
        acc4[c].y += a * wv.y;
        acc4[c].z += a * wv.z;
        acc4[c].w += a * wv.w;
      }
    }
  }
  u32 pk[16];
  for (int c = 0; c < 8; ++c) {
    pk[c * 2 + 0] = (u32)f2bf(acc4[c].x) | ((u32)f2bf(acc4[c].y) << 16);
    pk[c * 2 + 1] = (u32)f2bf(acc4[c].z) | ((u32)f2bf(acc4[c].w) << 16);
  }
  uint4* op = (uint4*)&h2[(long long)row * D_EMB];
  op[0] = make_uint4(pk[0], pk[1], pk[2], pk[3]);
  op[1] = make_uint4(pk[4], pk[5], pk[6], pk[7]);
  op[2] = make_uint4(pk[8], pk[9], pk[10], pk[11]);
  op[3] = make_uint4(pk[12], pk[13], pk[14], pk[15]);
}

// ---------------------------------------------------------------------------
// Decoder: scores[e] = dot(z2[src], z2[dst])  (bf16 rows, fp32 dot)
__global__ __launch_bounds__(256) void decode_kernel(
    const int* __restrict__ ei, const u16* __restrict__ z2,
    float* __restrict__ out, int nE) {
  const int e = blockIdx.x * 256 + threadIdx.x;
  if (e >= nE) return;
  const int s = ei[e];
  const int d = ei[nE + e];
  const uint4* za = (const uint4*)&z2[(long long)s * D_EMB];
  const uint4* zb = (const uint4*)&z2[(long long)d * D_EMB];
  float acc = 0.f;
  for (int c = 0; c < 4; ++c) {
    float a8[8], b8[8];
    unpack8(za[c], a8);
    unpack8(zb[c], b8);
    for (int k = 0; k < 8; ++k) acc = fmaf(a8[k], b8[k], acc);
  }
  out[e] = acc;
}

// ---------------------------------------------------------------------------
extern "C" void kernel_launch(void* const* d_in, const int* in_sizes, int n_in,
                              void* d_out, int out_size, void* d_ws, size_t ws_size,
                              hipStream_t stream) {
  const float* x       = (const float*)d_in[0];
  const int*   adj_src = (const int*)d_in[1];
  const int*   adj_dst = (const int*)d_in[2];
  const float* adj_val = (const float*)d_in[3];
  const int*   ei      = (const int*)d_in[4];
  const float* W1      = (const float*)d_in[5];
  const float* b1      = (const float*)d_in[6];
  const float* W2      = (const float*)d_in[7];
  const float* b2      = (const float*)d_in[8];

  const int M   = in_sizes[0] / D_IN;      // 100000
  const int nnz = in_sizes[1];             // 3200000
  const int nE  = in_sizes[4] / 2;         // 2000000

  const int NBUK = (M + BROWS - 1) / BROWS;  // 391

  // Workspace (76.8 MB):
  //   [0, 12.8):     csr packed u32 (src:17 | val:15)
  //   [12.8, 38.4):  payload int2 (dead after sort) -> h1 bf16 (12.8), h2 reuse
  //   [38.4, 51.2):  z1 bf16 (12.8), z2 reuse
  char* ws = (char*)d_ws;
  u32*   csr     = (u32*)(ws);
  int2*  payload = (int2*)(ws + (size_t)nnz * 4);
  u16*   h1      = (u16*)(ws + (size_t)nnz * 4);   // overwrites payload
  u16*   z1      = (u16*)(ws + (size_t)nnz * 4 + (size_t)nnz * 8);
  u16*   h2      = h1;
  u16*   z2      = z1;

  // Small scratch in d_out (8 MB, dead until decode):
  int* rs    = (int*)d_out;                 // M ints
  int* bscan = (int*)d_out + 112 * 1024;    // NBUK+1 ints
  int* cur   = (int*)d_out + 120 * 1024;    // NBUK ints

  // --- bucket partition ---
  hipMemsetAsync(bscan, 0, (size_t)(NBUK + 1) * 4, stream);
  bin_count<<<256, 256, 0, stream>>>(adj_dst, bscan, nnz, NBUK);
  bin_scan<<<1, 256, 0, stream>>>(bscan, cur, NBUK);
  partition_kernel<<<(nnz + TILE - 1) / TILE, 256, 0, stream>>>(
      adj_src, adj_dst, adj_val, cur, payload, nnz, NBUK);

  // --- bucket-local counting sort -> packed CSR + rs ---
  bucket_sort_kernel<<<NBUK, 256, 0, stream>>>(bscan, payload, csr, rs, M);

  // --- GEMM1 (bf16 out; overwrites payload region) ---
  gemm1_kernel<<<(M + 63) / 64, 256, 0, stream>>>(x, W1, h1, M);

  // --- SPMM1 + b1 + ReLU ---
  spmm_csr_kernel<D_HID, true><<<(M + 3) / 4, 256, 0, stream>>>(
      rs, csr, h1, b1, z1, M);

  // --- GEMM2 ---
  gemm2_kernel<<<(M + 255) / 256, 256, 0, stream>>>(z1, W2, h2, M);

  // --- SPMM2 + b2 ---
  spmm_csr_kernel<D_EMB, false><<<(M + 7) / 8, 256, 0, stream>>>(
      rs, csr, h2, b2, z2, M);

  // --- Decode (overwrites d_out scratch) ---
  decode_kernel<<<(nE + 255) / 256, 256, 0, stream>>>(ei, z2, (float*)d_out, nE);
}

// Round 7
// 529.743 us; speedup vs baseline: 5.6074x; 1.0946x over previous
//
#include <hip/hip_runtime.h>
#include <hip/hip_bf16.h>

// GCN link predictor, Round 7: MFMA GEMM1 (bf16, zero-LDS) + pre-swizzled W1.
//
// R6 postmortem: gemm1 top at 105us — 64KB LDS => 2 blocks/CU, Occ 18%,
// VALUBusy 26%: latency-capped, ~5x off its ~20us roofline (3.28 GFLOP,
// x read 102MB half-L3-resident). CDNA4 has no fp32 MFMA, but features are
// already bf16 — so round x/W1 to bf16 and use v_mfma_f32_16x16x32_bf16.
// W1 is pre-swizzled once into B-fragment order (32KB global, L2-resident):
//   A[m=lane&15][k=(lane>>4)*8+j], B[n=lane&15][k=(lane>>4)*8+j],
//   C/D: col=lane&15, row=(lane>>4)*4+reg   (guide m89/m120-verified).
// gemm1_mfma: 4 waves/block x 16 rows/wave x 64 cols, K=256 = 32 MFMA/wave,
// no LDS (occupancy VGPR-limited), A packed on the fly from fp32 x.
// Rest of pipeline unchanged from R6.

#define D_IN  256
#define D_HID 64
#define D_EMB 32
#define BROWS 256       // dst-rows per bucket
#define NBUK_MAX 512    // >= ceil(M/BROWS) = 391
#define TILE  4096      // edges per partition tile (16/thread)

typedef unsigned short u16;
typedef unsigned int u32;
typedef __attribute__((ext_vector_type(8))) short short8;   // 8 bf16
typedef __attribute__((ext_vector_type(4))) float f32x4;

__device__ __forceinline__ float bf2f(u32 u) {
  return __uint_as_float((u & 0xFFFFu) << 16);
}
__device__ __forceinline__ u16 f2bf(float f) {
  u32 x = __float_as_uint(f);
  x += 0x7FFFu + ((x >> 16) & 1u);  // RNE
  return (u16)(x >> 16);
}
__device__ __forceinline__ void unpack8(uint4 u, float* f) {
  f[0] = bf2f(u.x); f[1] = bf2f(u.x >> 16);
  f[2] = bf2f(u.y); f[3] = bf2f(u.y >> 16);
  f[4] = bf2f(u.z); f[5] = bf2f(u.z >> 16);
  f[6] = bf2f(u.w); f[7] = bf2f(u.w >> 16);
}

// ---------------------------------------------------------------------------
// One-time W1 swizzle: fp32 [256,64] -> bf16 B-fragments.
// slot s = (nt*8 + kstep)*64 + lane ; 8 bf16: W1[kstep*32+(lane>>4)*8+j][nt*16+(lane&15)]
__global__ __launch_bounds__(256) void w1_swizzle_kernel(
    const float* __restrict__ W1, uint4* __restrict__ gswz) {
  const int s = blockIdx.x * 256 + threadIdx.x;  // 2048 slots
  const int lane = s & 63;
  const int kstep = (s >> 6) & 7;
  const int nt = s >> 9;
  const int col = nt * 16 + (lane & 15);
  const int kbase = kstep * 32 + (lane >> 4) * 8;
  u32 p[4];
  for (int jp = 0; jp < 4; ++jp) {
    u32 lo = f2bf(W1[(kbase + 2 * jp) * D_HID + col]);
    u32 hi = f2bf(W1[(kbase + 2 * jp + 1) * D_HID + col]);
    p[jp] = lo | (hi << 16);
  }
  gswz[s] = make_uint4(p[0], p[1], p[2], p[3]);
}

// ---------------------------------------------------------------------------
// GEMM1 via MFMA: h1[M,64](bf16) = x[M,256](f32, rounded to bf16) @ W1.
// Block = 256 (4 waves); wave = rows [blk*64 + wv*16, +16), all 64 cols.
__global__ __launch_bounds__(256) void gemm1_mfma_kernel(
    const float* __restrict__ x, const uint4* __restrict__ gswz,
    u16* __restrict__ h1, int M) {
  const int tid = threadIdx.x;
  const int wv = tid >> 6;
  const int lane = tid & 63;
  const int quad = lane >> 4;
  const int m = lane & 15;

  const int rowbase = blockIdx.x * 64 + wv * 16;
  int arow = rowbase + m;
  if (arow >= M) arow = M - 1;  // clamp loads; stores guarded

  f32x4 acc[4];
  for (int nt = 0; nt < 4; ++nt) acc[nt] = (f32x4){0.f, 0.f, 0.f, 0.f};

  const float* xrow = &x[(long long)arow * D_IN];

#pragma unroll
  for (int kstep = 0; kstep < 8; ++kstep) {
    const int kbase = kstep * 32 + quad * 8;
    float4 a0 = *(const float4*)&xrow[kbase];
    float4 a1 = *(const float4*)&xrow[kbase + 4];
    short8 af;
    af[0] = (short)f2bf(a0.x); af[1] = (short)f2bf(a0.y);
    af[2] = (short)f2bf(a0.z); af[3] = (short)f2bf(a0.w);
    af[4] = (short)f2bf(a1.x); af[5] = (short)f2bf(a1.y);
    af[6] = (short)f2bf(a1.z); af[7] = (short)f2bf(a1.w);
#pragma unroll
    for (int nt = 0; nt < 4; ++nt) {
      uint4 bu = gswz[(nt * 8 + kstep) * 64 + lane];
      short8 bf = *(short8*)&bu;
      acc[nt] = __builtin_amdgcn_mfma_f32_16x16x32_bf16(af, bf, acc[nt], 0, 0, 0);
    }
  }

  // C/D: row = quad*4 + r, col = nt*16 + m
#pragma unroll
  for (int nt = 0; nt < 4; ++nt) {
#pragma unroll
    for (int r = 0; r < 4; ++r) {
      int orow = rowbase + quad * 4 + r;
      if (orow < M)
        h1[(long long)orow * D_HID + nt * 16 + m] = f2bf(acc[nt][r]);
    }
  }
}

// ---------------------------------------------------------------------------
// Bucket histogram (LDS-staged).
__global__ __launch_bounds__(256) void bin_count(
    const int* __restrict__ dst, int* __restrict__ hist, int nnz, int nbuk) {
  __shared__ int h[NBUK_MAX];
  for (int i = threadIdx.x; i < nbuk; i += 256) h[i] = 0;
  __syncthreads();
  const int stride = gridDim.x * 256;
  for (int e = blockIdx.x * 256 + threadIdx.x; e < nnz; e += stride)
    atomicAdd(&h[dst[e] >> 8], 1);
  __syncthreads();
  for (int i = threadIdx.x; i < nbuk; i += 256) {
    int v = h[i];
    if (v) atomicAdd(&hist[i], v);
  }
}

// 1-block exclusive scan (in place), copy to cur, sentinel hist[n] = total.
__global__ __launch_bounds__(256) void bin_scan(
    int* __restrict__ hist, int* __restrict__ cur, int n) {
  __shared__ int sm[256];
  const int t = threadIdx.x;
  const int per = (n + 255) / 256;
  const int base = t * per;
  int loc[4];
  int s = 0;
  for (int i = 0; i < per; ++i) {
    int idx = base + i;
    int v = (idx < n) ? hist[idx] : 0;
    loc[i] = s;
    s += v;
  }
  sm[t] = s;
  __syncthreads();
  for (int off = 1; off < 256; off <<= 1) {
    int tmp = (t >= off) ? sm[t - off] : 0;
    __syncthreads();
    sm[t] += tmp;
    __syncthreads();
  }
  const int b0 = sm[t] - s;
  for (int i = 0; i < per; ++i) {
    int idx = base + i;
    if (idx < n) {
      int p = b0 + loc[i];
      hist[idx] = p;
      cur[idx] = p;
    }
  }
  if (t == 255) hist[n] = sm[255];
}

// ---------------------------------------------------------------------------
// Tile-staged partition: LDS histogram -> scan -> one global reservation per
// (tile,bucket) -> LDS counting sort -> contiguous run writes.
__global__ __launch_bounds__(256) void partition_kernel(
    const int* __restrict__ src, const int* __restrict__ dst,
    const float* __restrict__ val, int* __restrict__ cur,
    int2* __restrict__ payload, int nnz, int nbuk) {
  __shared__ int2 stage[TILE];            // 32 KB
  __shared__ u16 sbkt[TILE];              // 8 KB
  __shared__ int hist[NBUK_MAX];
  __shared__ int lcur[NBUK_MAX];
  __shared__ int gbase[NBUK_MAX];
  __shared__ int sm[256];

  const int t = threadIdx.x;
  const long long base = (long long)blockIdx.x * TILE;
  const int cnt = min(TILE, (int)(nnz - base));

  for (int i = t; i < nbuk; i += 256) hist[i] = 0;
  __syncthreads();

  constexpr int PER = TILE / 256;  // 16
  int key[PER], vv[PER];
  short bk[PER];
  for (int i = 0; i < PER; ++i) {
    int idx = t + i * 256;
    if (idx < cnt) {
      int d = dst[base + idx];
      int b = d >> 8;
      bk[i] = (short)b;
      key[i] = (src[base + idx] << 8) | (d & (BROWS - 1));
      vv[i] = __float_as_int(val[base + idx]);
      atomicAdd(&hist[b], 1);
    } else {
      bk[i] = -1;
    }
  }
  __syncthreads();

  {
    const int per = (nbuk + 255) / 256;  // 2
    int c[4], loc[4];
    int s = 0;
    for (int i = 0; i < per; ++i) {
      int idx = t * per + i;
      c[i] = (idx < nbuk) ? hist[idx] : 0;
      loc[i] = s;
      s += c[i];
    }
    sm[t] = s;
    __syncthreads();
    for (int off = 1; off < 256; off <<= 1) {
      int tmp = (t >= off) ? sm[t - off] : 0;
      __syncthreads();
      sm[t] += tmp;
      __syncthreads();
    }
    const int b0 = sm[t] - s;
    for (int i = 0; i < per; ++i) {
      int idx = t * per + i;
      if (idx < nbuk) {
        int off = b0 + loc[i];
        hist[idx] = off;
        lcur[idx] = off;
        if (c[i] > 0) gbase[idx] = atomicAdd(&cur[idx], c[i]);
      }
    }
  }
  __syncthreads();

  for (int i = 0; i < PER; ++i) {
    if (bk[i] >= 0) {
      int p = atomicAdd(&lcur[bk[i]], 1);
      stage[p] = make_int2(key[i], vv[i]);
      sbkt[p] = (u16)bk[i];
    }
  }
  __syncthreads();

  for (int i = t; i < cnt; i += 256) {
    int b = sbkt[i];
    payload[gbase[b] + (i - hist[b])] = stage[i];
  }
}

// ---------------------------------------------------------------------------
// Bucket-local counting sort -> 4B packed CSR (src:17b | val:15b fixed-point)
// + global inclusive row scan rs. One block per bucket.
__global__ __launch_bounds__(256) void bucket_sort_kernel(
    const int* __restrict__ bscan, const int2* __restrict__ payload,
    u32* __restrict__ csr, int* __restrict__ rs, int M) {
  __shared__ int sm[BROWS];
  __shared__ int cur[BROWS];
  const int b = blockIdx.x;
  const int t = threadIdx.x;
  const int start = bscan[b];
  const int end = bscan[b + 1];

  cur[t] = 0;
  __syncthreads();
  for (int j = start + t; j < end; j += 256)
    atomicAdd(&cur[payload[j].x & (BROWS - 1)], 1);
  __syncthreads();

  const int v = cur[t];
  sm[t] = v;
  __syncthreads();
  for (int off = 1; off < 256; off <<= 1) {
    int tmp = (t >= off) ? sm[t - off] : 0;
    __syncthreads();
    sm[t] += tmp;
    __syncthreads();
  }
  const int row = b * BROWS + t;
  if (row < M) rs[row] = start + sm[t];
  __syncthreads();
  cur[t] = start + sm[t] - v;
  __syncthreads();

  for (int j = start + t; j < end; j += 256) {
    int2 pk = payload[j];
    int r = pk.x & (BROWS - 1);
    int p = atomicAdd(&cur[r], 1);
    float fv = __int_as_float(pk.y);
    int q = (int)(fv * 32768.f + 0.5f);
    q = min(q, 32767);
    csr[p] = ((u32)(pk.x >> 8) << 15) | (u32)q;
  }
}

// ---------------------------------------------------------------------------
// Row-team CSR SPMM (bf16 in/out, fp32 accum). rs = inclusive row scan.
template <int D, bool RELU>
__global__ __launch_bounds__(256) void spmm_csr_kernel(
    const int* __restrict__ rs, const u32* __restrict__ csr,
    const u16* __restrict__ in, const float* __restrict__ bias,
    u16* __restrict__ out, int M) {
  const int lane = threadIdx.x % D;
  const int row = blockIdx.x * (256 / D) + threadIdx.x / D;
  if (row >= M) return;
  const int start = (row == 0) ? 0 : rs[row - 1];
  const int end = rs[row];
  const float qs = 1.f / 32768.f;
  float acc = 0.f;
  int j = start;
  for (; j + 4 <= end; j += 4) {
    u32 p0 = csr[j], p1 = csr[j + 1], p2 = csr[j + 2], p3 = csr[j + 3];
    float x0 = bf2f(in[(long long)(p0 >> 15) * D + lane]);
    float x1 = bf2f(in[(long long)(p1 >> 15) * D + lane]);
    float x2 = bf2f(in[(long long)(p2 >> 15) * D + lane]);
    float x3 = bf2f(in[(long long)(p3 >> 15) * D + lane]);
    acc = fmaf((float)(p0 & 32767u) * qs, x0, acc);
    acc = fmaf((float)(p1 & 32767u) * qs, x1, acc);
    acc = fmaf((float)(p2 & 32767u) * qs, x2, acc);
    acc = fmaf((float)(p3 & 32767u) * qs, x3, acc);
  }
  for (; j < end; ++j) {
    u32 pk = csr[j];
    acc = fmaf((float)(pk & 32767u) * qs,
               bf2f(in[(long long)(pk >> 15) * D + lane]), acc);
  }
  float r = acc + bias[lane];
  if (RELU) r = fmaxf(r, 0.f);
  out[(long long)row * D + lane] = f2bf(r);
}

// ---------------------------------------------------------------------------
// GEMM2: h2[M,32](bf16) = z1[M,64](bf16) @ W2[64,32](f32)
__global__ __launch_bounds__(256) void gemm2_kernel(
    const u16* __restrict__ z1, const float* __restrict__ W2,
    u16* __restrict__ h2, int M) {
  __shared__ float ws[D_HID * D_EMB];
  const int tid = threadIdx.x;
  for (int i = tid; i < D_HID * D_EMB / 4; i += 256)
    ((float4*)ws)[i] = ((const float4*)W2)[i];
  __syncthreads();

  const int row = blockIdx.x * 256 + tid;
  if (row >= M) return;

  float4 acc4[8];
  for (int c = 0; c < 8; ++c) acc4[c] = make_float4(0.f, 0.f, 0.f, 0.f);

  const uint4* zr = (const uint4*)&z1[(long long)row * D_HID];
  for (int blk = 0; blk < 8; ++blk) {
    float a8[8];
    unpack8(zr[blk], a8);
    for (int kk = 0; kk < 8; ++kk) {
      const float a = a8[kk];
      const float4* wr = (const float4*)&ws[(blk * 8 + kk) * D_EMB];
      for (int c = 0; c < 8; ++c) {
        float4 wv = wr[c];
        acc4[c].x += a * wv.x;
        acc4[c].y += a * wv.y;
        acc4[c].z += a * wv.z;
        acc4[c].w += a * wv.w;
      }
    }
  }
  u32 pk[16];
  for (int c = 0; c < 8; ++c) {
    pk[c * 2 + 0] = (u32)f2bf(acc4[c].x) | ((u32)f2bf(acc4[c].y) << 16);
    pk[c * 2 + 1] = (u32)f2bf(acc4[c].z) | ((u32)f2bf(acc4[c].w) << 16);
  }
  uint4* op = (uint4*)&h2[(long long)row * D_EMB];
  op[0] = make_uint4(pk[0], pk[1], pk[2], pk[3]);
  op[1] = make_uint4(pk[4], pk[5], pk[6], pk[7]);
  op[2] = make_uint4(pk[8], pk[9], pk[10], pk[11]);
  op[3] = make_uint4(pk[12], pk[13], pk[14], pk[15]);
}

// ---------------------------------------------------------------------------
// Decoder: scores[e] = dot(z2[src], z2[dst])  (bf16 rows, fp32 dot)
__global__ __launch_bounds__(256) void decode_kernel(
    const int* __restrict__ ei, const u16* __restrict__ z2,
    float* __restrict__ out, int nE) {
  const int e = blockIdx.x * 256 + threadIdx.x;
  if (e >= nE) return;
  const int s = ei[e];
  const int d = ei[nE + e];
  const uint4* za = (const uint4*)&z2[(long long)s * D_EMB];
  const uint4* zb = (const uint4*)&z2[(long long)d * D_EMB];
  float acc = 0.f;
  for (int c = 0; c < 4; ++c) {
    float a8[8], b8[8];
    unpack8(za[c], a8);
    unpack8(zb[c], b8);
    for (int k = 0; k < 8; ++k) acc = fmaf(a8[k], b8[k], acc);
  }
  out[e] = acc;
}

// ---------------------------------------------------------------------------
extern "C" void kernel_launch(void* const* d_in, const int* in_sizes, int n_in,
                              void* d_out, int out_size, void* d_ws, size_t ws_size,
                              hipStream_t stream) {
  const float* x       = (const float*)d_in[0];
  const int*   adj_src = (const int*)d_in[1];
  const int*   adj_dst = (const int*)d_in[2];
  const float* adj_val = (const float*)d_in[3];
  const int*   ei      = (const int*)d_in[4];
  const float* W1      = (const float*)d_in[5];
  const float* b1      = (const float*)d_in[6];
  const float* W2      = (const float*)d_in[7];
  const float* b2      = (const float*)d_in[8];

  const int M   = in_sizes[0] / D_IN;      // 100000
  const int nnz = in_sizes[1];             // 3200000
  const int nE  = in_sizes[4] / 2;         // 2000000

  const int NBUK = (M + BROWS - 1) / BROWS;  // 391

  // Workspace (76.8 MB):
  //   [0, 12.8):     csr packed u32 (src:17 | val:15)
  //   [12.8, 38.4):  payload int2 (dead after sort) -> h1 bf16 (12.8), h2 reuse
  //   [38.4, 51.2):  z1 bf16 (12.8), z2 reuse
  //   [60.0, +32KB): gswz (pre-swizzled W1 bf16 fragments)
  char* ws = (char*)d_ws;
  u32*   csr     = (u32*)(ws);
  int2*  payload = (int2*)(ws + (size_t)nnz * 4);
  u16*   h1      = (u16*)(ws + (size_t)nnz * 4);   // overwrites payload
  u16*   z1      = (u16*)(ws + (size_t)nnz * 4 + (size_t)nnz * 8);
  u16*   h2      = h1;
  u16*   z2      = z1;
  uint4* gswz    = (uint4*)(ws + 60ull * 1024 * 1024);

  // Small scratch in d_out (8 MB, dead until decode):
  int* rs    = (int*)d_out;                 // M ints
  int* bscan = (int*)d_out + 112 * 1024;    // NBUK+1 ints
  int* cur   = (int*)d_out + 120 * 1024;    // NBUK ints

  // --- W1 swizzle (independent; 2048 slots) ---
  w1_swizzle_kernel<<<8, 256, 0, stream>>>(W1, gswz);

  // --- bucket partition ---
  hipMemsetAsync(bscan, 0, (size_t)(NBUK + 1) * 4, stream);
  bin_count<<<256, 256, 0, stream>>>(adj_dst, bscan, nnz, NBUK);
  bin_scan<<<1, 256, 0, stream>>>(bscan, cur, NBUK);
  partition_kernel<<<(nnz + TILE - 1) / TILE, 256, 0, stream>>>(
      adj_src, adj_dst, adj_val, cur, payload, nnz, NBUK);

  // --- bucket-local counting sort -> packed CSR + rs ---
  bucket_sort_kernel<<<NBUK, 256, 0, stream>>>(bscan, payload, csr, rs, M);

  // --- GEMM1 via MFMA (bf16 out; overwrites payload region) ---
  gemm1_mfma_kernel<<<(M + 63) / 64, 256, 0, stream>>>(x, gswz, h1, M);

  // --- SPMM1 + b1 + ReLU ---
  spmm_csr_kernel<D_HID, true><<<(M + 3) / 4, 256, 0, stream>>>(
      rs, csr, h1, b1, z1, M);

  // --- GEMM2 ---
  gemm2_kernel<<<(M + 255) / 256, 256, 0, stream>>>(z1, W2, h2, M);

  // --- SPMM2 + b2 ---
  spmm_csr_kernel<D_EMB, false><<<(M + 7) / 8, 256, 0, stream>>>(
      rs, csr, h2, b2, z2, M);

  // --- Decode (overwrites d_out scratch) ---
  decode_kernel<<<(nE + 255) / 256, 256, 0, stream>>>(ei, z2, (float*)d_out, nE);
}

// Round 8
// 463.617 us; speedup vs baseline: 6.4072x; 1.1426x over previous
//
#include <hip/hip_runtime.h>
#include <hip/hip_bf16.h>

// GCN link predictor, Round 8: team-vectorized SPMM (uint2/lane, 16-lane teams).
//
// R7 postmortem: spmm_csr<64> top at 103us, VALUBusy 56%, FETCH 152MB —
// VALU-bound: 64 lanes/row x 2B loads means ~10 VALU/edge/lane for 128B of
// gather. R8: 16-lane teams, each lane loads uint2 (4 bf16 dims) => per-edge
// VALU drops ~2.5x; csr[j] is a team-uniform broadcast; same 128B/edge
// traffic; output write stays a contiguous 128B per team.
// Rest unchanged from R7 (MFMA gemm1 + swizzled W1, tile partition,
// bucket sort -> 4B packed CSR, bf16 features, fused biases).

#define D_IN  256
#define D_HID 64
#define D_EMB 32
#define BROWS 256       // dst-rows per bucket
#define NBUK_MAX 512    // >= ceil(M/BROWS) = 391
#define TILE  4096      // edges per partition tile (16/thread)

typedef unsigned short u16;
typedef unsigned int u32;
typedef __attribute__((ext_vector_type(8))) short short8;   // 8 bf16
typedef __attribute__((ext_vector_type(4))) float f32x4;

__device__ __forceinline__ float bf2f(u32 u) {
  return __uint_as_float((u & 0xFFFFu) << 16);
}
__device__ __forceinline__ float bf2f_hi(u32 u) {
  return __uint_as_float(u & 0xFFFF0000u);
}
__device__ __forceinline__ u16 f2bf(float f) {
  u32 x = __float_as_uint(f);
  x += 0x7FFFu + ((x >> 16) & 1u);  // RNE
  return (u16)(x >> 16);
}
__device__ __forceinline__ void unpack8(uint4 u, float* f) {
  f[0] = bf2f(u.x); f[1] = bf2f(u.x >> 16);
  f[2] = bf2f(u.y); f[3] = bf2f(u.y >> 16);
  f[4] = bf2f(u.z); f[5] = bf2f(u.z >> 16);
  f[6] = bf2f(u.w); f[7] = bf2f(u.w >> 16);
}

// ---------------------------------------------------------------------------
// One-time W1 swizzle: fp32 [256,64] -> bf16 B-fragments.
__global__ __launch_bounds__(256) void w1_swizzle_kernel(
    const float* __restrict__ W1, uint4* __restrict__ gswz) {
  const int s = blockIdx.x * 256 + threadIdx.x;  // 2048 slots
  const int lane = s & 63;
  const int kstep = (s >> 6) & 7;
  const int nt = s >> 9;
  const int col = nt * 16 + (lane & 15);
  const int kbase = kstep * 32 + (lane >> 4) * 8;
  u32 p[4];
  for (int jp = 0; jp < 4; ++jp) {
    u32 lo = f2bf(W1[(kbase + 2 * jp) * D_HID + col]);
    u32 hi = f2bf(W1[(kbase + 2 * jp + 1) * D_HID + col]);
    p[jp] = lo | (hi << 16);
  }
  gswz[s] = make_uint4(p[0], p[1], p[2], p[3]);
}

// ---------------------------------------------------------------------------
// GEMM1 via MFMA: h1[M,64](bf16) = x[M,256](f32 -> bf16) @ W1.
__global__ __launch_bounds__(256) void gemm1_mfma_kernel(
    const float* __restrict__ x, const uint4* __restrict__ gswz,
    u16* __restrict__ h1, int M) {
  const int tid = threadIdx.x;
  const int wv = tid >> 6;
  const int lane = tid & 63;
  const int quad = lane >> 4;
  const int m = lane & 15;

  const int rowbase = blockIdx.x * 64 + wv * 16;
  int arow = rowbase + m;
  if (arow >= M) arow = M - 1;

  f32x4 acc[4];
  for (int nt = 0; nt < 4; ++nt) acc[nt] = (f32x4){0.f, 0.f, 0.f, 0.f};

  const float* xrow = &x[(long long)arow * D_IN];

#pragma unroll
  for (int kstep = 0; kstep < 8; ++kstep) {
    const int kbase = kstep * 32 + quad * 8;
    float4 a0 = *(const float4*)&xrow[kbase];
    float4 a1 = *(const float4*)&xrow[kbase + 4];
    short8 af;
    af[0] = (short)f2bf(a0.x); af[1] = (short)f2bf(a0.y);
    af[2] = (short)f2bf(a0.z); af[3] = (short)f2bf(a0.w);
    af[4] = (short)f2bf(a1.x); af[5] = (short)f2bf(a1.y);
    af[6] = (short)f2bf(a1.z); af[7] = (short)f2bf(a1.w);
#pragma unroll
    for (int nt = 0; nt < 4; ++nt) {
      uint4 bu = gswz[(nt * 8 + kstep) * 64 + lane];
      short8 bf = *(short8*)&bu;
      acc[nt] = __builtin_amdgcn_mfma_f32_16x16x32_bf16(af, bf, acc[nt], 0, 0, 0);
    }
  }

#pragma unroll
  for (int nt = 0; nt < 4; ++nt) {
#pragma unroll
    for (int r = 0; r < 4; ++r) {
      int orow = rowbase + quad * 4 + r;
      if (orow < M)
        h1[(long long)orow * D_HID + nt * 16 + m] = f2bf(acc[nt][r]);
    }
  }
}

// ---------------------------------------------------------------------------
// Bucket histogram (LDS-staged).
__global__ __launch_bounds__(256) void bin_count(
    const int* __restrict__ dst, int* __restrict__ hist, int nnz, int nbuk) {
  __shared__ int h[NBUK_MAX];
  for (int i = threadIdx.x; i < nbuk; i += 256) h[i] = 0;
  __syncthreads();
  const int stride = gridDim.x * 256;
  for (int e = blockIdx.x * 256 + threadIdx.x; e < nnz; e += stride)
    atomicAdd(&h[dst[e] >> 8], 1);
  __syncthreads();
  for (int i = threadIdx.x; i < nbuk; i += 256) {
    int v = h[i];
    if (v) atomicAdd(&hist[i], v);
  }
}

// 1-block exclusive scan (in place), copy to cur, sentinel hist[n] = total.
__global__ __launch_bounds__(256) void bin_scan(
    int* __restrict__ hist, int* __restrict__ cur, int n) {
  __shared__ int sm[256];
  const int t = threadIdx.x;
  const int per = (n + 255) / 256;
  const int base = t * per;
  int loc[4];
  int s = 0;
  for (int i = 0; i < per; ++i) {
    int idx = base + i;
    int v = (idx < n) ? hist[idx] : 0;
    loc[i] = s;
    s += v;
  }
  sm[t] = s;
  __syncthreads();
  for (int off = 1; off < 256; off <<= 1) {
    int tmp = (t >= off) ? sm[t - off] : 0;
    __syncthreads();
    sm[t] += tmp;
    __syncthreads();
  }
  const int b0 = sm[t] - s;
  for (int i = 0; i < per; ++i) {
    int idx = base + i;
    if (idx < n) {
      int p = b0 + loc[i];
      hist[idx] = p;
      cur[idx] = p;
    }
  }
  if (t == 255) hist[n] = sm[255];
}

// ---------------------------------------------------------------------------
// Tile-staged partition.
__global__ __launch_bounds__(256) void partition_kernel(
    const int* __restrict__ src, const int* __restrict__ dst,
    const float* __restrict__ val, int* __restrict__ cur,
    int2* __restrict__ payload, int nnz, int nbuk) {
  __shared__ int2 stage[TILE];            // 32 KB
  __shared__ u16 sbkt[TILE];              // 8 KB
  __shared__ int hist[NBUK_MAX];
  __shared__ int lcur[NBUK_MAX];
  __shared__ int gbase[NBUK_MAX];
  __shared__ int sm[256];

  const int t = threadIdx.x;
  const long long base = (long long)blockIdx.x * TILE;
  const int cnt = min(TILE, (int)(nnz - base));

  for (int i = t; i < nbuk; i += 256) hist[i] = 0;
  __syncthreads();

  constexpr int PER = TILE / 256;  // 16
  int key[PER], vv[PER];
  short bk[PER];
  for (int i = 0; i < PER; ++i) {
    int idx = t + i * 256;
    if (idx < cnt) {
      int d = dst[base + idx];
      int b = d >> 8;
      bk[i] = (short)b;
      key[i] = (src[base + idx] << 8) | (d & (BROWS - 1));
      vv[i] = __float_as_int(val[base + idx]);
      atomicAdd(&hist[b], 1);
    } else {
      bk[i] = -1;
    }
  }
  __syncthreads();

  {
    const int per = (nbuk + 255) / 256;  // 2
    int c[4], loc[4];
    int s = 0;
    for (int i = 0; i < per; ++i) {
      int idx = t * per + i;
      c[i] = (idx < nbuk) ? hist[idx] : 0;
      loc[i] = s;
      s += c[i];
    }
    sm[t] = s;
    __syncthreads();
    for (int off = 1; off < 256; off <<= 1) {
      int tmp = (t >= off) ? sm[t - off] : 0;
      __syncthreads();
      sm[t] += tmp;
      __syncthreads();
    }
    const int b0 = sm[t] - s;
    for (int i = 0; i < per; ++i) {
      int idx = t * per + i;
      if (idx < nbuk) {
        int off = b0 + loc[i];
        hist[idx] = off;
        lcur[idx] = off;
        if (c[i] > 0) gbase[idx] = atomicAdd(&cur[idx], c[i]);
      }
    }
  }
  __syncthreads();

  for (int i = 0; i < PER; ++i) {
    if (bk[i] >= 0) {
      int p = atomicAdd(&lcur[bk[i]], 1);
      stage[p] = make_int2(key[i], vv[i]);
      sbkt[p] = (u16)bk[i];
    }
  }
  __syncthreads();

  for (int i = t; i < cnt; i += 256) {
    int b = sbkt[i];
    payload[gbase[b] + (i - hist[b])] = stage[i];
  }
}

// ---------------------------------------------------------------------------
// Bucket-local counting sort -> 4B packed CSR (src:17 | val:15 fixed-point)
// + global inclusive row scan rs.
__global__ __launch_bounds__(256) void bucket_sort_kernel(
    const int* __restrict__ bscan, const int2* __restrict__ payload,
    u32* __restrict__ csr, int* __restrict__ rs, int M) {
  __shared__ int sm[BROWS];
  __shared__ int cur[BROWS];
  const int b = blockIdx.x;
  const int t = threadIdx.x;
  const int start = bscan[b];
  const int end = bscan[b + 1];

  cur[t] = 0;
  __syncthreads();
  for (int j = start + t; j < end; j += 256)
    atomicAdd(&cur[payload[j].x & (BROWS - 1)], 1);
  __syncthreads();

  const int v = cur[t];
  sm[t] = v;
  __syncthreads();
  for (int off = 1; off < 256; off <<= 1) {
    int tmp = (t >= off) ? sm[t - off] : 0;
    __syncthreads();
    sm[t] += tmp;
    __syncthreads();
  }
  const int row = b * BROWS + t;
  if (row < M) rs[row] = start + sm[t];
  __syncthreads();
  cur[t] = start + sm[t] - v;
  __syncthreads();

  for (int j = start + t; j < end; j += 256) {
    int2 pk = payload[j];
    int r = pk.x & (BROWS - 1);
    int p = atomicAdd(&cur[r], 1);
    float fv = __int_as_float(pk.y);
    int q = (int)(fv * 32768.f + 0.5f);
    q = min(q, 32767);
    csr[p] = ((u32)(pk.x >> 8) << 15) | (u32)q;
  }
}

// ---------------------------------------------------------------------------
// Team-vectorized CSR SPMM: TEAM = D/4 lanes per row, each lane owns 4 dims
// (one uint2 = 4 bf16 per edge). csr[j] is team-uniform (broadcast).
template <int D, bool RELU>
__global__ __launch_bounds__(256) void spmm_csr_kernel(
    const int* __restrict__ rs, const u32* __restrict__ csr,
    const u16* __restrict__ in, const float* __restrict__ bias,
    u16* __restrict__ out, int M) {
  constexpr int TEAM = D / 4;
  const int lt = threadIdx.x % TEAM;             // lane in team
  const int row = blockIdx.x * (256 / TEAM) + threadIdx.x / TEAM;
  if (row >= M) return;
  const int start = (row == 0) ? 0 : rs[row - 1];
  const int end = rs[row];
  const float qs = 1.f / 32768.f;
  const u16* inp = in + lt * 4;

  float a0 = 0.f, a1 = 0.f, a2 = 0.f, a3 = 0.f;
  int j = start;
  for (; j + 4 <= end; j += 4) {
    u32 p0 = csr[j], p1 = csr[j + 1], p2 = csr[j + 2], p3 = csr[j + 3];
    uint2 w0 = *(const uint2*)&inp[(long long)(p0 >> 15) * D];
    uint2 w1 = *(const uint2*)&inp[(long long)(p1 >> 15) * D];
    uint2 w2 = *(const uint2*)&inp[(long long)(p2 >> 15) * D];
    uint2 w3 = *(const uint2*)&inp[(long long)(p3 >> 15) * D];
    float v0 = (float)(p0 & 32767u) * qs;
    float v1 = (float)(p1 & 32767u) * qs;
    float v2 = (float)(p2 & 32767u) * qs;
    float v3 = (float)(p3 & 32767u) * qs;
    a0 = fmaf(v0, bf2f(w0.x), a0); a1 = fmaf(v0, bf2f_hi(w0.x), a1);
    a2 = fmaf(v0, bf2f(w0.y), a2); a3 = fmaf(v0, bf2f_hi(w0.y), a3);
    a0 = fmaf(v1, bf2f(w1.x), a0); a1 = fmaf(v1, bf2f_hi(w1.x), a1);
    a2 = fmaf(v1, bf2f(w1.y), a2); a3 = fmaf(v1, bf2f_hi(w1.y), a3);
    a0 = fmaf(v2, bf2f(w2.x), a0); a1 = fmaf(v2, bf2f_hi(w2.x), a1);
    a2 = fmaf(v2, bf2f(w2.y), a2); a3 = fmaf(v2, bf2f_hi(w2.y), a3);
    a0 = fmaf(v3, bf2f(w3.x), a0); a1 = fmaf(v3, bf2f_hi(w3.x), a1);
    a2 = fmaf(v3, bf2f(w3.y), a2); a3 = fmaf(v3, bf2f_hi(w3.y), a3);
  }
  for (; j < end; ++j) {
    u32 pk = csr[j];
    uint2 w = *(const uint2*)&inp[(long long)(pk >> 15) * D];
    float v = (float)(pk & 32767u) * qs;
    a0 = fmaf(v, bf2f(w.x), a0); a1 = fmaf(v, bf2f_hi(w.x), a1);
    a2 = fmaf(v, bf2f(w.y), a2); a3 = fmaf(v, bf2f_hi(w.y), a3);
  }
  const float4 bv = *(const float4*)&bias[lt * 4];
  a0 += bv.x; a1 += bv.y; a2 += bv.z; a3 += bv.w;
  if (RELU) {
    a0 = fmaxf(a0, 0.f); a1 = fmaxf(a1, 0.f);
    a2 = fmaxf(a2, 0.f); a3 = fmaxf(a3, 0.f);
  }
  uint2 o;
  o.x = (u32)f2bf(a0) | ((u32)f2bf(a1) << 16);
  o.y = (u32)f2bf(a2) | ((u32)f2bf(a3) << 16);
  *(uint2*)&out[(long long)row * D + lt * 4] = o;
}

// ---------------------------------------------------------------------------
// GEMM2: h2[M,32](bf16) = z1[M,64](bf16) @ W2[64,32](f32)
__global__ __launch_bounds__(256) void gemm2_kernel(
    const u16* __restrict__ z1, const float* __restrict__ W2,
    u16* __restrict__ h2, int M) {
  __shared__ float ws[D_HID * D_EMB];
  const int tid = threadIdx.x;
  for (int i = tid; i < D_HID * D_EMB / 4; i += 256)
    ((float4*)ws)[i] = ((const float4*)W2)[i];
  __syncthreads();

  const int row = blockIdx.x * 256 + tid;
  if (row >= M) return;

  float4 acc4[8];
  for (int c = 0; c < 8; ++c) acc4[c] = make_float4(0.f, 0.f, 0.f, 0.f);

  const uint4* zr = (const uint4*)&z1[(long long)row * D_HID];
  for (int blk = 0; blk < 8; ++blk) {
    float a8[8];
    unpack8(zr[blk], a8);
    for (int kk = 0; kk < 8; ++kk) {
      const float a = a8[kk];
      const float4* wr = (const float4*)&ws[(blk * 8 + kk) * D_EMB];
      for (int c = 0; c < 8; ++c) {
        float4 wv = wr[c];
        acc4[c].x += a * wv.x;
        acc4[c].y += a * wv.y;
        acc4[c].z += a * wv.z;
        acc4[c].w += a * wv.w;
      }
    }
  }
  u32 pk[16];
  for (int c = 0; c < 8; ++c) {
    pk[c * 2 + 0] = (u32)f2bf(acc4[c].x) | ((u32)f2bf(acc4[c].y) << 16);
    pk[c * 2 + 1] = (u32)f2bf(acc4[c].z) | ((u32)f2bf(acc4[c].w) << 16);
  }
  uint4* op = (uint4*)&h2[(long long)row * D_EMB];
  op[0] = make_uint4(pk[0], pk[1], pk[2], pk[3]);
  op[1] = make_uint4(pk[4], pk[5], pk[6], pk[7]);
  op[2] = make_uint4(pk[8], pk[9], pk[10], pk[11]);
  op[3] = make_uint4(pk[12], pk[13], pk[14], pk[15]);
}

// ---------------------------------------------------------------------------
// Decoder: scores[e] = dot(z2[src], z2[dst])  (bf16 rows, fp32 dot)
__global__ __launch_bounds__(256) void decode_kernel(
    const int* __restrict__ ei, const u16* __restrict__ z2,
    float* __restrict__ out, int nE) {
  const int e = blockIdx.x * 256 + threadIdx.x;
  if (e >= nE) return;
  const int s = ei[e];
  const int d = ei[nE + e];
  const uint4* za = (const uint4*)&z2[(long long)s * D_EMB];
  const uint4* zb = (const uint4*)&z2[(long long)d * D_EMB];
  float acc = 0.f;
  for (int c = 0; c < 4; ++c) {
    float a8[8], b8[8];
    unpack8(za[c], a8);
    unpack8(zb[c], b8);
    for (int k = 0; k < 8; ++k) acc = fmaf(a8[k], b8[k], acc);
  }
  out[e] = acc;
}

// ---------------------------------------------------------------------------
extern "C" void kernel_launch(void* const* d_in, const int* in_sizes, int n_in,
                              void* d_out, int out_size, void* d_ws, size_t ws_size,
                              hipStream_t stream) {
  const float* x       = (const float*)d_in[0];
  const int*   adj_src = (const int*)d_in[1];
  const int*   adj_dst = (const int*)d_in[2];
  const float* adj_val = (const float*)d_in[3];
  const int*   ei      = (const int*)d_in[4];
  const float* W1      = (const float*)d_in[5];
  const float* b1      = (const float*)d_in[6];
  const float* W2      = (const float*)d_in[7];
  const float* b2      = (const float*)d_in[8];

  const int M   = in_sizes[0] / D_IN;      // 100000
  const int nnz = in_sizes[1];             // 3200000
  const int nE  = in_sizes[4] / 2;         // 2000000

  const int NBUK = (M + BROWS - 1) / BROWS;  // 391

  // Workspace (76.8 MB):
  //   [0, 12.8):     csr packed u32
  //   [12.8, 38.4):  payload int2 (dead after sort) -> h1 bf16, h2 reuse
  //   [38.4, 51.2):  z1 bf16, z2 reuse
  //   [60.0, +32KB): gswz (pre-swizzled W1 bf16 fragments)
  char* ws = (char*)d_ws;
  u32*   csr     = (u32*)(ws);
  int2*  payload = (int2*)(ws + (size_t)nnz * 4);
  u16*   h1      = (u16*)(ws + (size_t)nnz * 4);
  u16*   z1      = (u16*)(ws + (size_t)nnz * 4 + (size_t)nnz * 8);
  u16*   h2      = h1;
  u16*   z2      = z1;
  uint4* gswz    = (uint4*)(ws + 60ull * 1024 * 1024);

  // Small scratch in d_out (8 MB, dead until decode):
  int* rs    = (int*)d_out;                 // M ints
  int* bscan = (int*)d_out + 112 * 1024;    // NBUK+1 ints
  int* cur   = (int*)d_out + 120 * 1024;    // NBUK ints

  // --- W1 swizzle ---
  w1_swizzle_kernel<<<8, 256, 0, stream>>>(W1, gswz);

  // --- bucket partition ---
  hipMemsetAsync(bscan, 0, (size_t)(NBUK + 1) * 4, stream);
  bin_count<<<256, 256, 0, stream>>>(adj_dst, bscan, nnz, NBUK);
  bin_scan<<<1, 256, 0, stream>>>(bscan, cur, NBUK);
  partition_kernel<<<(nnz + TILE - 1) / TILE, 256, 0, stream>>>(
      adj_src, adj_dst, adj_val, cur, payload, nnz, NBUK);

  // --- bucket-local counting sort -> packed CSR + rs ---
  bucket_sort_kernel<<<NBUK, 256, 0, stream>>>(bscan, payload, csr, rs, M);

  // --- GEMM1 via MFMA ---
  gemm1_mfma_kernel<<<(M + 63) / 64, 256, 0, stream>>>(x, gswz, h1, M);

  // --- SPMM1 + b1 + ReLU (16-lane teams, 16 rows/block) ---
  spmm_csr_kernel<D_HID, true><<<(M + 15) / 16, 256, 0, stream>>>(
      rs, csr, h1, b1, z1, M);

  // --- GEMM2 ---
  gemm2_kernel<<<(M + 255) / 256, 256, 0, stream>>>(z1, W2, h2, M);

  // --- SPMM2 + b2 (8-lane teams, 32 rows/block) ---
  spmm_csr_kernel<D_EMB, false><<<(M + 31) / 32, 256, 0, stream>>>(
      rs, csr, h2, b2, z2, M);

  // --- Decode (overwrites d_out scratch) ---
  decode_kernel<<<(nE + 255) / 256, 256, 0, stream>>>(ei, z2, (float*)d_out, nE);
}

// Round 9
// 431.731 us; speedup vs baseline: 6.8804x; 1.0739x over previous
//
#include <hip/hip_runtime.h>
#include <hip/hip_bf16.h>

// GCN link predictor, Round 9: occupancy fix for the partition phase.
//
// R8 postmortem: partition_kernel top at 62us — NOT conflicts (1.2M cycles /
// 256 CU = noise), NOT traffic (19+34MB = ~9us HBM): 48KB LDS => 3 blocks/CU,
// Occ 22%, VALUBusy 5% -> latency-bound. bucket_sort has the same disease
// (391 blocks x 256 thr = 1.5 blocks/CU).
//
// R9: partition at 512 threads + sbkt deleted (bucket<<15|q15 packed into
// payload.y; val quantization moved here) => 40KB LDS, 4 blocks x 8 waves =
// 32 waves/CU (max). bucket_sort at 1024 threads (16 waves/block), scan by
// first 256 lanes; csr emit becomes pure bit-ops.
// Rest unchanged from R8 (MFMA gemm1, 16-lane-team SPMM, bf16 features,
// 4B packed CSR, fused biases).

#define D_IN  256
#define D_HID 64
#define D_EMB 32
#define BROWS 256       // dst-rows per bucket
#define NBUK_MAX 512    // >= ceil(M/BROWS) = 391
#define TILE  4096      // edges per partition tile
#define PBS   512       // partition block size (PER = 8)
#define SBS   1024      // bucket_sort block size

typedef unsigned short u16;
typedef unsigned int u32;
typedef __attribute__((ext_vector_type(8))) short short8;   // 8 bf16
typedef __attribute__((ext_vector_type(4))) float f32x4;

__device__ __forceinline__ float bf2f(u32 u) {
  return __uint_as_float((u & 0xFFFFu) << 16);
}
__device__ __forceinline__ float bf2f_hi(u32 u) {
  return __uint_as_float(u & 0xFFFF0000u);
}
__device__ __forceinline__ u16 f2bf(float f) {
  u32 x = __float_as_uint(f);
  x += 0x7FFFu + ((x >> 16) & 1u);  // RNE
  return (u16)(x >> 16);
}
__device__ __forceinline__ void unpack8(uint4 u, float* f) {
  f[0] = bf2f(u.x); f[1] = bf2f(u.x >> 16);
  f[2] = bf2f(u.y); f[3] = bf2f(u.y >> 16);
  f[4] = bf2f(u.z); f[5] = bf2f(u.z >> 16);
  f[6] = bf2f(u.w); f[7] = bf2f(u.w >> 16);
}

// ---------------------------------------------------------------------------
// One-time W1 swizzle: fp32 [256,64] -> bf16 B-fragments.
__global__ __launch_bounds__(256) void w1_swizzle_kernel(
    const float* __restrict__ W1, uint4* __restrict__ gswz) {
  const int s = blockIdx.x * 256 + threadIdx.x;  // 2048 slots
  const int lane = s & 63;
  const int kstep = (s >> 6) & 7;
  const int nt = s >> 9;
  const int col = nt * 16 + (lane & 15);
  const int kbase = kstep * 32 + (lane >> 4) * 8;
  u32 p[4];
  for (int jp = 0; jp < 4; ++jp) {
    u32 lo = f2bf(W1[(kbase + 2 * jp) * D_HID + col]);
    u32 hi = f2bf(W1[(kbase + 2 * jp + 1) * D_HID + col]);
    p[jp] = lo | (hi << 16);
  }
  gswz[s] = make_uint4(p[0], p[1], p[2], p[3]);
}

// ---------------------------------------------------------------------------
// GEMM1 via MFMA: h1[M,64](bf16) = x[M,256](f32 -> bf16) @ W1.
__global__ __launch_bounds__(256) void gemm1_mfma_kernel(
    const float* __restrict__ x, const uint4* __restrict__ gswz,
    u16* __restrict__ h1, int M) {
  const int tid = threadIdx.x;
  const int wv = tid >> 6;
  const int lane = tid & 63;
  const int quad = lane >> 4;
  const int m = lane & 15;

  const int rowbase = blockIdx.x * 64 + wv * 16;
  int arow = rowbase + m;
  if (arow >= M) arow = M - 1;

  f32x4 acc[4];
  for (int nt = 0; nt < 4; ++nt) acc[nt] = (f32x4){0.f, 0.f, 0.f, 0.f};

  const float* xrow = &x[(long long)arow * D_IN];

#pragma unroll
  for (int kstep = 0; kstep < 8; ++kstep) {
    const int kbase = kstep * 32 + quad * 8;
    float4 a0 = *(const float4*)&xrow[kbase];
    float4 a1 = *(const float4*)&xrow[kbase + 4];
    short8 af;
    af[0] = (short)f2bf(a0.x); af[1] = (short)f2bf(a0.y);
    af[2] = (short)f2bf(a0.z); af[3] = (short)f2bf(a0.w);
    af[4] = (short)f2bf(a1.x); af[5] = (short)f2bf(a1.y);
    af[6] = (short)f2bf(a1.z); af[7] = (short)f2bf(a1.w);
#pragma unroll
    for (int nt = 0; nt < 4; ++nt) {
      uint4 bu = gswz[(nt * 8 + kstep) * 64 + lane];
      short8 bf = *(short8*)&bu;
      acc[nt] = __builtin_amdgcn_mfma_f32_16x16x32_bf16(af, bf, acc[nt], 0, 0, 0);
    }
  }

#pragma unroll
  for (int nt = 0; nt < 4; ++nt) {
#pragma unroll
    for (int r = 0; r < 4; ++r) {
      int orow = rowbase + quad * 4 + r;
      if (orow < M)
        h1[(long long)orow * D_HID + nt * 16 + m] = f2bf(acc[nt][r]);
    }
  }
}

// ---------------------------------------------------------------------------
// Bucket histogram (LDS-staged).
__global__ __launch_bounds__(256) void bin_count(
    const int* __restrict__ dst, int* __restrict__ hist, int nnz, int nbuk) {
  __shared__ int h[NBUK_MAX];
  for (int i = threadIdx.x; i < nbuk; i += 256) h[i] = 0;
  __syncthreads();
  const int stride = gridDim.x * 256;
  for (int e = blockIdx.x * 256 + threadIdx.x; e < nnz; e += stride)
    atomicAdd(&h[dst[e] >> 8], 1);
  __syncthreads();
  for (int i = threadIdx.x; i < nbuk; i += 256) {
    int v = h[i];
    if (v) atomicAdd(&hist[i], v);
  }
}

// 1-block exclusive scan (in place), copy to cur, sentinel hist[n] = total.
__global__ __launch_bounds__(256) void bin_scan(
    int* __restrict__ hist, int* __restrict__ cur, int n) {
  __shared__ int sm[256];
  const int t = threadIdx.x;
  const int per = (n + 255) / 256;
  const int base = t * per;
  int loc[4];
  int s = 0;
  for (int i = 0; i < per; ++i) {
    int idx = base + i;
    int v = (idx < n) ? hist[idx] : 0;
    loc[i] = s;
    s += v;
  }
  sm[t] = s;
  __syncthreads();
  for (int off = 1; off < 256; off <<= 1) {
    int tmp = (t >= off) ? sm[t - off] : 0;
    __syncthreads();
    sm[t] += tmp;
    __syncthreads();
  }
  const int b0 = sm[t] - s;
  for (int i = 0; i < per; ++i) {
    int idx = base + i;
    if (idx < n) {
      int p = b0 + loc[i];
      hist[idx] = p;
      cur[idx] = p;
    }
  }
  if (t == 255) hist[n] = sm[255];
}

// ---------------------------------------------------------------------------
// Tile-staged partition, 512 threads, 40KB LDS => 4 blocks/CU (32 waves).
// payload: .x = src<<8 | dstlow, .y = bucket<<15 | q15(val).
__global__ __launch_bounds__(PBS) void partition_kernel(
    const int* __restrict__ src, const int* __restrict__ dst,
    const float* __restrict__ val, int* __restrict__ cur,
    int2* __restrict__ payload, int nnz, int nbuk) {
  __shared__ int2 stage[TILE];            // 32 KB
  __shared__ int hist[NBUK_MAX];          // 2 KB: counts -> local excl offsets
  __shared__ int lcur[NBUK_MAX];          // 2 KB
  __shared__ int gbase[NBUK_MAX];         // 2 KB
  __shared__ int sm[PBS];                 // 2 KB

  const int t = threadIdx.x;
  const long long base = (long long)blockIdx.x * TILE;
  const int cnt = min(TILE, (int)(nnz - base));

  for (int i = t; i < nbuk; i += PBS) hist[i] = 0;
  __syncthreads();

  constexpr int PER = TILE / PBS;  // 8
  int key[PER], vq[PER];
  short bk[PER];
  for (int i = 0; i < PER; ++i) {
    int idx = t + i * PBS;
    if (idx < cnt) {
      int d = dst[base + idx];
      int b = d >> 8;
      bk[i] = (short)b;
      key[i] = (src[base + idx] << 8) | (d & (BROWS - 1));
      int q = (int)(val[base + idx] * 32768.f + 0.5f);
      q = min(q, 32767);
      vq[i] = (b << 15) | q;
      atomicAdd(&hist[b], 1);
    } else {
      bk[i] = -1;
    }
  }
  __syncthreads();

  // scan hist (nbuk <= PBS) -> exclusive offsets; reserve global chunks
  {
    int c = (t < nbuk) ? hist[t] : 0;
    sm[t] = c;
    __syncthreads();
    for (int off = 1; off < PBS; off <<= 1) {
      int tmp = (t >= off) ? sm[t - off] : 0;
      __syncthreads();
      sm[t] += tmp;
      __syncthreads();
    }
    int excl = sm[t] - c;
    if (t < nbuk) {
      hist[t] = excl;
      lcur[t] = excl;
      if (c > 0) gbase[t] = atomicAdd(&cur[t], c);
    }
  }
  __syncthreads();

  // counting sort into stage
  for (int i = 0; i < PER; ++i) {
    if (bk[i] >= 0) {
      int p = atomicAdd(&lcur[bk[i]], 1);
      stage[p] = make_int2(key[i], vq[i]);
    }
  }
  __syncthreads();

  // contiguous run write-out (bucket recovered from .y)
  for (int i = t; i < cnt; i += PBS) {
    int2 pk = stage[i];
    int b = pk.y >> 15;
    payload[gbase[b] + (i - hist[b])] = pk;
  }
}

// ---------------------------------------------------------------------------
// Bucket-local counting sort -> 4B packed CSR (src:17 | q15) + inclusive rs.
// 1024 threads/block; scan by first 256 lanes.
__global__ __launch_bounds__(SBS) void bucket_sort_kernel(
    const int* __restrict__ bscan, const int2* __restrict__ payload,
    u32* __restrict__ csr, int* __restrict__ rs, int M) {
  __shared__ int cnt_s[BROWS];
  __shared__ int sm[BROWS];
  const int b = blockIdx.x;
  const int t = threadIdx.x;
  const int start = bscan[b];
  const int end = bscan[b + 1];

  if (t < BROWS) cnt_s[t] = 0;
  __syncthreads();
  for (int j = start + t; j < end; j += SBS)
    atomicAdd(&cnt_s[payload[j].x & (BROWS - 1)], 1);
  __syncthreads();

  int v = 0;
  if (t < BROWS) { v = cnt_s[t]; sm[t] = v; }
  __syncthreads();
  for (int off = 1; off < BROWS; off <<= 1) {
    int tmp = 0;
    if (t < BROWS && t >= off) tmp = sm[t - off];
    __syncthreads();
    if (t < BROWS) sm[t] += tmp;
    __syncthreads();
  }
  if (t < BROWS) {
    int row = b * BROWS + t;
    if (row < M) rs[row] = start + sm[t];    // inclusive row end
    cnt_s[t] = start + sm[t] - v;            // exclusive cursor
  }
  __syncthreads();

  for (int j = start + t; j < end; j += SBS) {
    int2 pk = payload[j];
    int r = pk.x & (BROWS - 1);
    int p = atomicAdd(&cnt_s[r], 1);
    csr[p] = ((u32)(pk.x >> 8) << 15) | (u32)(pk.y & 32767);
  }
}

// ---------------------------------------------------------------------------
// Team-vectorized CSR SPMM: TEAM = D/4 lanes per row, uint2 (4 bf16) per lane.
template <int D, bool RELU>
__global__ __launch_bounds__(256) void spmm_csr_kernel(
    const int* __restrict__ rs, const u32* __restrict__ csr,
    const u16* __restrict__ in, const float* __restrict__ bias,
    u16* __restrict__ out, int M) {
  constexpr int TEAM = D / 4;
  const int lt = threadIdx.x % TEAM;
  const int row = blockIdx.x * (256 / TEAM) + threadIdx.x / TEAM;
  if (row >= M) return;
  const int start = (row == 0) ? 0 : rs[row - 1];
  const int end = rs[row];
  const float qs = 1.f / 32768.f;
  const u16* inp = in + lt * 4;

  float a0 = 0.f, a1 = 0.f, a2 = 0.f, a3 = 0.f;
  int j = start;
  for (; j + 4 <= end; j += 4) {
    u32 p0 = csr[j], p1 = csr[j + 1], p2 = csr[j + 2], p3 = csr[j + 3];
    uint2 w0 = *(const uint2*)&inp[(long long)(p0 >> 15) * D];
    uint2 w1 = *(const uint2*)&inp[(long long)(p1 >> 15) * D];
    uint2 w2 = *(const uint2*)&inp[(long long)(p2 >> 15) * D];
    uint2 w3 = *(const uint2*)&inp[(long long)(p3 >> 15) * D];
    float v0 = (float)(p0 & 32767u) * qs;
    float v1 = (float)(p1 & 32767u) * qs;
    float v2 = (float)(p2 & 32767u) * qs;
    float v3 = (float)(p3 & 32767u) * qs;
    a0 = fmaf(v0, bf2f(w0.x), a0); a1 = fmaf(v0, bf2f_hi(w0.x), a1);
    a2 = fmaf(v0, bf2f(w0.y), a2); a3 = fmaf(v0, bf2f_hi(w0.y), a3);
    a0 = fmaf(v1, bf2f(w1.x), a0); a1 = fmaf(v1, bf2f_hi(w1.x), a1);
    a2 = fmaf(v1, bf2f(w1.y), a2); a3 = fmaf(v1, bf2f_hi(w1.y), a3);
    a0 = fmaf(v2, bf2f(w2.x), a0); a1 = fmaf(v2, bf2f_hi(w2.x), a1);
    a2 = fmaf(v2, bf2f(w2.y), a2); a3 = fmaf(v2, bf2f_hi(w2.y), a3);
    a0 = fmaf(v3, bf2f(w3.x), a0); a1 = fmaf(v3, bf2f_hi(w3.x), a1);
    a2 = fmaf(v3, bf2f(w3.y), a2); a3 = fmaf(v3, bf2f_hi(w3.y), a3);
  }
  for (; j < end; ++j) {
    u32 pk = csr[j];
    uint2 w = *(const uint2*)&inp[(long long)(pk >> 15) * D];
    float v = (float)(pk & 32767u) * qs;
    a0 = fmaf(v, bf2f(w.x), a0); a1 = fmaf(v, bf2f_hi(w.x), a1);
    a2 = fmaf(v, bf2f(w.y), a2); a3 = fmaf(v, bf2f_hi(w.y), a3);
  }
  const float4 bv = *(const float4*)&bias[lt * 4];
  a0 += bv.x; a1 += bv.y; a2 += bv.z; a3 += bv.w;
  if (RELU) {
    a0 = fmaxf(a0, 0.f); a1 = fmaxf(a1, 0.f);
    a2 = fmaxf(a2, 0.f); a3 = fmaxf(a3, 0.f);
  }
  uint2 o;
  o.x = (u32)f2bf(a0) | ((u32)f2bf(a1) << 16);
  o.y = (u32)f2bf(a2) | ((u32)f2bf(a3) << 16);
  *(uint2*)&out[(long long)row * D + lt * 4] = o;
}

// ---------------------------------------------------------------------------
// GEMM2: h2[M,32](bf16) = z1[M,64](bf16) @ W2[64,32](f32)
__global__ __launch_bounds__(256) void gemm2_kernel(
    const u16* __restrict__ z1, const float* __restrict__ W2,
    u16* __restrict__ h2, int M) {
  __shared__ float ws[D_HID * D_EMB];
  const int tid = threadIdx.x;
  for (int i = tid; i < D_HID * D_EMB / 4; i += 256)
    ((float4*)ws)[i] = ((const float4*)W2)[i];
  __syncthreads();

  const int row = blockIdx.x * 256 + tid;
  if (row >= M) return;

  float4 acc4[8];
  for (int c = 0; c < 8; ++c) acc4[c] = make_float4(0.f, 0.f, 0.f, 0.f);

  const uint4* zr = (const uint4*)&z1[(long long)row * D_HID];
  for (int blk = 0; blk < 8; ++blk) {
    float a8[8];
    unpack8(zr[blk], a8);
    for (int kk = 0; kk < 8; ++kk) {
      const float a = a8[kk];
      const float4* wr = (const float4*)&ws[(blk * 8 + kk) * D_EMB];
      for (int c = 0; c < 8; ++c) {
        float4 wv = wr[c];
        acc4[c].x += a * wv.x;
        acc4[c].y += a * wv.y;
        acc4[c].z += a * wv.z;
        acc4[c].w += a * wv.w;
      }
    }
  }
  u32 pk[16];
  for (int c = 0; c < 8; ++c) {
    pk[c * 2 + 0] = (u32)f2bf(acc4[c].x) | ((u32)f2bf(acc4[c].y) << 16);
    pk[c * 2 + 1] = (u32)f2bf(acc4[c].z) | ((u32)f2bf(acc4[c].w) << 16);
  }
  uint4* op = (uint4*)&h2[(long long)row * D_EMB];
  op[0] = make_uint4(pk[0], pk[1], pk[2], pk[3]);
  op[1] = make_uint4(pk[4], pk[5], pk[6], pk[7]);
  op[2] = make_uint4(pk[8], pk[9], pk[10], pk[11]);
  op[3] = make_uint4(pk[12], pk[13], pk[14], pk[15]);
}

// ---------------------------------------------------------------------------
// Decoder: scores[e] = dot(z2[src], z2[dst])  (bf16 rows, fp32 dot)
__global__ __launch_bounds__(256) void decode_kernel(
    const int* __restrict__ ei, const u16* __restrict__ z2,
    float* __restrict__ out, int nE) {
  const int e = blockIdx.x * 256 + threadIdx.x;
  if (e >= nE) return;
  const int s = ei[e];
  const int d = ei[nE + e];
  const uint4* za = (const uint4*)&z2[(long long)s * D_EMB];
  const uint4* zb = (const uint4*)&z2[(long long)d * D_EMB];
  float acc = 0.f;
  for (int c = 0; c < 4; ++c) {
    float a8[8], b8[8];
    unpack8(za[c], a8);
    unpack8(zb[c], b8);
    for (int k = 0; k < 8; ++k) acc = fmaf(a8[k], b8[k], acc);
  }
  out[e] = acc;
}

// ---------------------------------------------------------------------------
extern "C" void kernel_launch(void* const* d_in, const int* in_sizes, int n_in,
                              void* d_out, int out_size, void* d_ws, size_t ws_size,
                              hipStream_t stream) {
  const float* x       = (const float*)d_in[0];
  const int*   adj_src = (const int*)d_in[1];
  const int*   adj_dst = (const int*)d_in[2];
  const float* adj_val = (const float*)d_in[3];
  const int*   ei      = (const int*)d_in[4];
  const float* W1      = (const float*)d_in[5];
  const float* b1      = (const float*)d_in[6];
  const float* W2      = (const float*)d_in[7];
  const float* b2      = (const float*)d_in[8];

  const int M   = in_sizes[0] / D_IN;      // 100000
  const int nnz = in_sizes[1];             // 3200000
  const int nE  = in_sizes[4] / 2;         // 2000000

  const int NBUK = (M + BROWS - 1) / BROWS;  // 391

  // Workspace (76.8 MB):
  //   [0, 12.8):     csr packed u32
  //   [12.8, 38.4):  payload int2 (dead after sort) -> h1 bf16, h2 reuse
  //   [38.4, 51.2):  z1 bf16, z2 reuse
  //   [60.0, +32KB): gswz (pre-swizzled W1 bf16 fragments)
  char* ws = (char*)d_ws;
  u32*   csr     = (u32*)(ws);
  int2*  payload = (int2*)(ws + (size_t)nnz * 4);
  u16*   h1      = (u16*)(ws + (size_t)nnz * 4);
  u16*   z1      = (u16*)(ws + (size_t)nnz * 4 + (size_t)nnz * 8);
  u16*   h2      = h1;
  u16*   z2      = z1;
  uint4* gswz    = (uint4*)(ws + 60ull * 1024 * 1024);

  // Small scratch in d_out (8 MB, dead until decode):
  int* rs    = (int*)d_out;                 // M ints
  int* bscan = (int*)d_out + 112 * 1024;    // NBUK+1 ints
  int* cur   = (int*)d_out + 120 * 1024;    // NBUK ints

  // --- W1 swizzle ---
  w1_swizzle_kernel<<<8, 256, 0, stream>>>(W1, gswz);

  // --- bucket partition ---
  hipMemsetAsync(bscan, 0, (size_t)(NBUK + 1) * 4, stream);
  bin_count<<<256, 256, 0, stream>>>(adj_dst, bscan, nnz, NBUK);
  bin_scan<<<1, 256, 0, stream>>>(bscan, cur, NBUK);
  partition_kernel<<<(nnz + TILE - 1) / TILE, PBS, 0, stream>>>(
      adj_src, adj_dst, adj_val, cur, payload, nnz, NBUK);

  // --- bucket-local counting sort -> packed CSR + rs ---
  bucket_sort_kernel<<<NBUK, SBS, 0, stream>>>(bscan, payload, csr, rs, M);

  // --- GEMM1 via MFMA ---
  gemm1_mfma_kernel<<<(M + 63) / 64, 256, 0, stream>>>(x, gswz, h1, M);

  // --- SPMM1 + b1 + ReLU (16-lane teams) ---
  spmm_csr_kernel<D_HID, true><<<(M + 15) / 16, 256, 0, stream>>>(
      rs, csr, h1, b1, z1, M);

  // --- GEMM2 ---
  gemm2_kernel<<<(M + 255) / 256, 256, 0, stream>>>(z1, W2, h2, M);

  // --- SPMM2 + b2 (8-lane teams) ---
  spmm_csr_kernel<D_EMB, false><<<(M + 31) / 32, 256, 0, stream>>>(
      rs, csr, h2, b2, z2, M);

  // --- Decode (overwrites d_out scratch) ---
  decode_kernel<<<(nE + 255) / 256, 256, 0, stream>>>(ei, z2, (float*)d_out, nE);
}